// Round 6
// baseline (394.952 us; speedup 1.0000x reference)
//
#include <hip/hip_runtime.h>
#include <hip/hip_bf16.h>
#include <math.h>

// Problem constants
#define Bb   256
#define Nn   400
#define FIN  400
#define Hh   64
#define NNZ  16000
#define Mrows (Bb*Nn)          // 102400
#define KP   416               // dense-adj K padded to 13*32 for MFMA
#define UTP  416               // Ut node-dim stride (shorts), 16B-aligned rows
#define BH_COUNT 16384.0f      // B*H for BN3 stats

typedef unsigned int  u32x2 __attribute__((ext_vector_type(2)));
typedef unsigned int  u32x4 __attribute__((ext_vector_type(4)));
typedef __bf16        bf16x8 __attribute__((ext_vector_type(8)));
typedef float         f32x4 __attribute__((ext_vector_type(4)));

__device__ __forceinline__ unsigned int f2bf(float x) {
    unsigned int u = __builtin_bit_cast(unsigned int, x);
    return (u + 0x7FFFu + ((u >> 16) & 1u)) >> 16;   // RNE
}
__device__ __forceinline__ float bf2f(unsigned int h) {
    unsigned int u = h << 16;
    return __builtin_bit_cast(float, u);
}

// ---------------------------------------------------------------------------
// init: zero dense-A f32 accumulator, BN stats, Ut node-pad (400..415)
// ---------------------------------------------------------------------------
__global__ void initk(float* __restrict__ Adf, float* __restrict__ stats,
                      unsigned short* __restrict__ Ut) {
    int t = blockIdx.x * blockDim.x + threadIdx.x;
    if (t < Nn * KP) Adf[t] = 0.f;
    if (t < 1600) stats[t] = 0.f;   // ssum1, ssq1, ssum2, ssq2 (4 x 400)
    if (t < Bb * Hh * 16) {
        int bh = t >> 4, k = Nn + (t & 15);
        Ut[(size_t)bh * UTP + k] = 0;
    }
}

__global__ void scatAk(const int* __restrict__ rows, const int* __restrict__ cols,
                       const float* __restrict__ vals, float* __restrict__ Adf) {
    int i = blockIdx.x * blockDim.x + threadIdx.x;
    if (i < NNZ) atomicAdd(&Adf[rows[i] * KP + cols[i]], vals[i]);
}

__global__ void cvtAk(const float* __restrict__ Adf, unsigned short* __restrict__ Adbf) {
    int i = blockIdx.x * blockDim.x + threadIdx.x;
    if (i < Nn * KP) Adbf[i] = (unsigned short)f2bf(Adf[i]);
}

// ---------------------------------------------------------------------------
// W prep: split W[KT][64] -> hi/lo bf16 in B-fragment layout [col][KPAD]
// (k-major per column), plus colsum. block = one column of one W.
// ---------------------------------------------------------------------------
__global__ __launch_bounds__(256) void wprep(
        const float* __restrict__ W1, const float* __restrict__ W2,
        const float* __restrict__ W3,
        unsigned short* __restrict__ T1h, unsigned short* __restrict__ T1l,
        unsigned short* __restrict__ T2h, unsigned short* __restrict__ T2l,
        unsigned short* __restrict__ T3h, unsigned short* __restrict__ T3l,
        float* __restrict__ cs2, float* __restrict__ cs3) {
    const int w = blockIdx.x >> 6;        // 0,1,2
    const int c = blockIdx.x & 63;
    const float* W = (w == 0) ? W1 : (w == 1) ? W2 : W3;
    const int KT   = (w == 0) ? FIN : Hh;
    const int KPAD = (w == 0) ? 416 : 64;
    unsigned short* Th = (w == 0) ? T1h : (w == 1) ? T2h : T3h;
    unsigned short* Tl = (w == 0) ? T1l : (w == 1) ? T2l : T3l;

    float s = 0.f;
    for (int k = threadIdx.x; k < KPAD; k += 256) {
        float v = (k < KT) ? W[k * 64 + c] : 0.f;
        unsigned int hb = f2bf(v);
        Th[c * KPAD + k] = (unsigned short)hb;
        Tl[c * KPAD + k] = (unsigned short)f2bf(v - bf2f(hb));
        s += v;
    }
    __shared__ float red[256];
    red[threadIdx.x] = s;
    __syncthreads();
    for (int o = 128; o; o >>= 1) {
        if (threadIdx.x < o) red[threadIdx.x] += red[threadIdx.x + o];
        __syncthreads();
    }
    if (threadIdx.x == 0) {
        if (w == 1) cs2[c] = red[0];
        else if (w == 2) cs3[c] = red[0];
    }
}

// ---------------------------------------------------------------------------
// Split-precision MFMA GEMM, LDS-free:
//   Ut[b][col][node] (bf16) = A[M,KT](f32) @ W[KT,64]  (+ A-side BN affine)
// A split in-register (Ah+Al); W pre-split hi/lo in global fragment layout.
// acc += Ah*Wh + Ah*Wl + Al*Wh  (f32-grade). 4 waves x 16 rows = 64 rows/blk.
// Output written TRANSPOSED per batch: Ut[(b*64+col)*UTP + node], 8B packed
// (4-row groups never straddle a batch boundary since 400 % 4 == 0).
// ---------------------------------------------------------------------------
template <int KT, bool AFFINE>
__global__ __launch_bounds__(256) void xg(
        const float* __restrict__ A,
        const unsigned short* __restrict__ Wth,
        const unsigned short* __restrict__ Wtl,
        const float* __restrict__ csW,
        unsigned short* __restrict__ Ut,
        const float* __restrict__ mean, const float* __restrict__ inv) {
    constexpr int KPAD  = (KT == 400) ? 416 : 64;
    constexpr int NSTEP = (KT + 31) / 32;
    const int tid  = threadIdx.x;
    const int wv   = tid >> 6;      // 0..3
    const int lane = tid & 63;
    const int cl   = lane & 15;
    const int g    = lane >> 4;
    const int m0   = blockIdx.x * 64;
    const int arow = m0 + wv * 16 + cl;

    f32x4 acc[4];
#pragma unroll
    for (int n = 0; n < 4; ++n) acc[n] = f32x4{0.f, 0.f, 0.f, 0.f};

    for (int s = 0; s < NSTEP; ++s) {
        const int kk = s * 32 + g * 8;
        float av[8];
#pragma unroll
        for (int j = 0; j < 8; ++j) av[j] = 0.f;
        if ((KT & 31) == 0 || kk < KT) {
            const float* p = &A[(size_t)arow * KT + kk];
            float4 lo = *reinterpret_cast<const float4*>(p);
            float4 hi = *reinterpret_cast<const float4*>(p + 4);
            av[0] = lo.x; av[1] = lo.y; av[2] = lo.z; av[3] = lo.w;
            av[4] = hi.x; av[5] = hi.y; av[6] = hi.z; av[7] = hi.w;
        }
        u32x4 ahw, alw;
#pragma unroll
        for (int j = 0; j < 4; ++j) {
            unsigned int h0 = f2bf(av[2 * j]);
            unsigned int h1 = f2bf(av[2 * j + 1]);
            unsigned int l0 = f2bf(av[2 * j]     - bf2f(h0));
            unsigned int l1 = f2bf(av[2 * j + 1] - bf2f(h1));
            ahw[j] = h0 | (h1 << 16);
            alw[j] = l0 | (l1 << 16);
        }
        bf16x8 ah = __builtin_bit_cast(bf16x8, ahw);
        bf16x8 al = __builtin_bit_cast(bf16x8, alw);
#pragma unroll
        for (int n = 0; n < 4; ++n) {
            const size_t co = (size_t)(n * 16 + cl) * KPAD + kk;
            u32x4 bhw = *reinterpret_cast<const u32x4*>(&Wth[co]);
            u32x4 blw = *reinterpret_cast<const u32x4*>(&Wtl[co]);
            bf16x8 bh = __builtin_bit_cast(bf16x8, bhw);
            bf16x8 bl = __builtin_bit_cast(bf16x8, blw);
            acc[n] = __builtin_amdgcn_mfma_f32_16x16x32_bf16(ah, bh, acc[n], 0, 0, 0);
            acc[n] = __builtin_amdgcn_mfma_f32_16x16x32_bf16(ah, bl, acc[n], 0, 0, 0);
            acc[n] = __builtin_amdgcn_mfma_f32_16x16x32_bf16(al, bh, acc[n], 0, 0, 0);
        }
    }

    // epilogue: 4 consecutive rows (one batch), packed 8B transposed store
    const int row0  = m0 + wv * 16 + g * 4;
    const int b     = row0 / Nn;
    const int node0 = row0 - b * Nn;
    float mm[4], iv[4];
    if (AFFINE) {
#pragma unroll
        for (int r = 0; r < 4; ++r) { mm[r] = mean[node0 + r]; iv[r] = inv[node0 + r]; }
    }
#pragma unroll
    for (int n = 0; n < 4; ++n) {
        const int col = n * 16 + cl;
        float cw = AFFINE ? csW[col] : 0.f;
        float y[4];
#pragma unroll
        for (int r = 0; r < 4; ++r) {
            float v = acc[n][r];
            if (AFFINE) v = iv[r] * (v - mm[r] * cw);
            y[r] = v;
        }
        u32x2 pk;
        pk[0] = f2bf(y[0]) | (f2bf(y[1]) << 16);
        pk[1] = f2bf(y[2]) | (f2bf(y[3]) << 16);
        *reinterpret_cast<u32x2*>(&Ut[((size_t)b * 64 + col) * UTP + node0]) = pk;
    }
}

// ---------------------------------------------------------------------------
// Dense MFMA aggregation, LDS-free: Z[b] = normalize(Adj @ U[b] + bias)
//   STATS: + relu + BN3 stat atomics.
// 4 blocks per batch (q = blockIdx&3), 256 threads = 4 waves.
// A-frags from Adbf (L2-resident), B-frags from Ut[b] (L1/L2).
// Tiles: t = q + 4*wv + 16*i, i<2, guard t<25.
// ---------------------------------------------------------------------------
template <bool STATS>
__global__ __launch_bounds__(256) void aggmm(
        const unsigned short* __restrict__ Ad,   // [400][416] bf16 bits
        const unsigned short* __restrict__ Ut,   // [B*64][416] bf16 bits
        const float* __restrict__ bias,
        float* __restrict__ Zout,                // [B*400][64] f32
        float* __restrict__ ssum, float* __restrict__ ssq) {
    const int b    = blockIdx.x >> 2;
    const int q    = blockIdx.x & 3;
    const int tid  = threadIdx.x;
    const int lane = tid & 63;
    const int wv   = tid >> 6;
    const int cl   = lane & 15;
    const int g    = lane >> 4;
    const unsigned short* __restrict__ Ub = Ut + (size_t)b * 64 * UTP;

    f32x4 acc[2][4];
#pragma unroll
    for (int i = 0; i < 2; ++i)
#pragma unroll
        for (int n = 0; n < 4; ++n) acc[i][n] = f32x4{0.f, 0.f, 0.f, 0.f};

    for (int k0 = 0; k0 < KP; k0 += 32) {
        const int kk = k0 + g * 8;
        bf16x8 bf[4];
#pragma unroll
        for (int n = 0; n < 4; ++n) {
            u32x4 w = *reinterpret_cast<const u32x4*>(&Ub[(size_t)(n * 16 + cl) * UTP + kk]);
            bf[n] = __builtin_bit_cast(bf16x8, w);
        }
#pragma unroll
        for (int i = 0; i < 2; ++i) {
            const int t = q + 4 * wv + 16 * i;
            if (t < 25) {
                const int row = t * 16 + cl;
                u32x4 ar = *reinterpret_cast<const u32x4*>(&Ad[(size_t)row * KP + kk]);
                bf16x8 af = __builtin_bit_cast(bf16x8, ar);
#pragma unroll
                for (int n = 0; n < 4; ++n)
                    acc[i][n] = __builtin_amdgcn_mfma_f32_16x16x32_bf16(
                        af, bf[n], acc[i][n], 0, 0, 0);
            }
        }
    }

    float bv[4];
#pragma unroll
    for (int n = 0; n < 4; ++n) bv[n] = bias[n * 16 + cl];

#pragma unroll
    for (int i = 0; i < 2; ++i) {
        const int t = q + 4 * wv + 16 * i;
        if (t < 25) {
            float y[4][4];
#pragma unroll
            for (int n = 0; n < 4; ++n)
#pragma unroll
                for (int r = 0; r < 4; ++r) y[n][r] = acc[i][n][r] + bv[n];

            float pss[4];
#pragma unroll
            for (int r = 0; r < 4; ++r)
                pss[r] = y[0][r]*y[0][r] + y[1][r]*y[1][r] +
                         y[2][r]*y[2][r] + y[3][r]*y[3][r];
#pragma unroll
            for (int m = 1; m < 16; m <<= 1)
#pragma unroll
                for (int r = 0; r < 4; ++r) pss[r] += __shfl_xor(pss[r], m);

            float rin[4];
#pragma unroll
            for (int r = 0; r < 4; ++r)
                rin[r] = 1.f / fmaxf(sqrtf(pss[r]), 1e-12f);

#pragma unroll
            for (int n = 0; n < 4; ++n)
#pragma unroll
                for (int r = 0; r < 4; ++r) {
                    float z = y[n][r] * rin[r];
                    if (STATS) z = fmaxf(z, 0.f);
                    y[n][r] = z;
                    const int row = t * 16 + g * 4 + r;
                    Zout[((size_t)b * Nn + row) * Hh + n * 16 + cl] = z;
                }

            if (STATS) {
                float s1[4], s2[4];
#pragma unroll
                for (int r = 0; r < 4; ++r) {
                    s1[r] = y[0][r] + y[1][r] + y[2][r] + y[3][r];
                    s2[r] = y[0][r]*y[0][r] + y[1][r]*y[1][r] +
                            y[2][r]*y[2][r] + y[3][r]*y[3][r];
                }
#pragma unroll
                for (int m = 1; m < 16; m <<= 1)
#pragma unroll
                    for (int r = 0; r < 4; ++r) {
                        s1[r] += __shfl_xor(s1[r], m);
                        s2[r] += __shfl_xor(s2[r], m);
                    }
                if (cl == 0) {
#pragma unroll
                    for (int r = 0; r < 4; ++r) {
                        const int row = t * 16 + g * 4 + r;
                        atomicAdd(&ssum[row], s1[r]);
                        atomicAdd(&ssq[row],  s2[r]);
                    }
                }
            }
        }
    }
}

__global__ void finalize_stats(const float* __restrict__ ssum,
                               const float* __restrict__ ssq,
                               float* __restrict__ mean, float* __restrict__ inv) {
    int r = threadIdx.x;
    if (r < Nn) {
        float m = ssum[r] * (1.0f / BH_COUNT);
        float v = ssq[r] * (1.0f / BH_COUNT) - m * m;
        mean[r] = m;
        inv[r]  = rsqrtf(v + 1e-5f);
    }
}

// ---------------------------------------------------------------------------
// out[b,h] = max_r affine(Z[b,r,h])   (AFF = BN3; else identity)
// ---------------------------------------------------------------------------
template <bool AFF>
__global__ __launch_bounds__(256) void maxk(
        const float* __restrict__ Z, const float* __restrict__ mean,
        const float* __restrict__ inv, float* __restrict__ out) {
    __shared__ float red[4][64];
    const int b  = blockIdx.x;
    const int h  = threadIdx.x & 63;
    const int rg = threadIdx.x >> 6;
    float best = -3.4e38f;
    for (int r = rg; r < Nn; r += 4) {
        float v = Z[((size_t)b * Nn + r) * Hh + h];
        if (AFF) v = (v - mean[r]) * inv[r];
        best = fmaxf(best, v);
    }
    red[rg][h] = best;
    __syncthreads();
    if (threadIdx.x < 64) {
        float m = fmaxf(fmaxf(red[0][threadIdx.x], red[1][threadIdx.x]),
                        fmaxf(red[2][threadIdx.x], red[3][threadIdx.x]));
        out[b * Hh + threadIdx.x] = m;
    }
}

// ---------------------------------------------------------------------------
// FC head: h=[out1|out2|out3] (256x192) -> fc1+relu+bn2 -> fc2+relu+bn2 -> fc3
// ---------------------------------------------------------------------------
__global__ __launch_bounds__(1024) void headk(
        const float* __restrict__ out1, const float* __restrict__ out2,
        const float* __restrict__ out3,
        const float* __restrict__ W1f, const float* __restrict__ b1f,
        const float* __restrict__ W2f, const float* __restrict__ b2f,
        const float* __restrict__ W3f, const float* __restrict__ b3f,
        float* __restrict__ ypred) {
    __shared__ float gA[256][64];     // 64 KB activations
    __shared__ float w1s[192 * 64];   // 48 KB
    __shared__ float w2s[64 * 64];    // 16 KB
    __shared__ float mS[64], iS[64];
    const int t = threadIdx.x;
    const int r = t >> 2, q = t & 3;

    for (int i = t; i < 192 * 64; i += 1024) w1s[i] = W1f[i];
    for (int i = t; i < 64 * 64; i += 1024) w2s[i] = W2f[i];
    __syncthreads();

    float acc[16];
#pragma unroll
    for (int j = 0; j < 16; ++j) acc[j] = b1f[q * 16 + j];
    for (int k = 0; k < 192; ++k) {
        float hv = (k < 64) ? out1[r * 64 + k]
                 : (k < 128) ? out2[r * 64 + (k - 64)]
                             : out3[r * 64 + (k - 128)];
#pragma unroll
        for (int j = 0; j < 16; ++j) acc[j] += hv * w1s[k * 64 + q * 16 + j];
    }
#pragma unroll
    for (int j = 0; j < 16; ++j) gA[r][q * 16 + j] = fmaxf(acc[j], 0.f);
    __syncthreads();

    if (t < 64) {
        float s = 0.f, s2 = 0.f;
        for (int rr = 0; rr < 256; ++rr) { float v = gA[rr][t]; s += v; s2 += v * v; }
        float m = s * (1.f / 256.f);
        float var = s2 * (1.f / 256.f) - m * m;
        mS[t] = m;
        iS[t] = rsqrtf(var + 1e-5f);
    }
    __syncthreads();

#pragma unroll
    for (int j = 0; j < 16; ++j) acc[j] = b2f[q * 16 + j];
#pragma unroll
    for (int k = 0; k < 64; ++k) {
        float gn = (gA[r][k] - mS[k]) * iS[k];
#pragma unroll
        for (int j = 0; j < 16; ++j) acc[j] += gn * w2s[k * 64 + q * 16 + j];
    }
    __syncthreads();
#pragma unroll
    for (int j = 0; j < 16; ++j) gA[r][q * 16 + j] = fmaxf(acc[j], 0.f);
    __syncthreads();

    if (t < 64) {
        float s = 0.f, s2 = 0.f;
        for (int rr = 0; rr < 256; ++rr) { float v = gA[rr][t]; s += v; s2 += v * v; }
        float m = s * (1.f / 256.f);
        float var = s2 * (1.f / 256.f) - m * m;
        mS[t] = m;
        iS[t] = rsqrtf(var + 1e-5f);
    }
    __syncthreads();

    if (q < 2) {
        float a = b3f[q];
#pragma unroll
        for (int k = 0; k < 64; ++k) {
            float gn = (gA[r][k] - mS[k]) * iS[k];
            a += gn * W3f[k * 2 + q];
        }
        ypred[r * 2 + q] = a;
    }
}

// ---------------------------------------------------------------------------
extern "C" void kernel_launch(void* const* d_in, const int* in_sizes, int n_in,
                              void* d_out, int out_size, void* d_ws, size_t ws_size,
                              hipStream_t stream) {
    const float* x    = (const float*)d_in[0];
    const int*   arow = (const int*)d_in[1];
    const int*   acol = (const int*)d_in[2];
    const float* aval = (const float*)d_in[3];
    const float* W1 = (const float*)d_in[4];
    const float* b1 = (const float*)d_in[5];
    const float* W2 = (const float*)d_in[6];
    const float* b2 = (const float*)d_in[7];
    const float* W3 = (const float*)d_in[8];
    const float* b3 = (const float*)d_in[9];
    const float* fc1W = (const float*)d_in[10];
    const float* fc1b = (const float*)d_in[11];
    const float* fc2W = (const float*)d_in[12];
    const float* fc2b = (const float*)d_in[13];
    const float* fc3W = (const float*)d_in[14];
    const float* fc3b = (const float*)d_in[15];

    char* w = (char*)d_ws;
    size_t off = 0;
    float* Adf = (float*)(w + off);            off += (size_t)Nn * KP * 4;
    unsigned short* Adbf = (unsigned short*)(w + off); off += (size_t)Nn * KP * 2;
    unsigned short* T1h = (unsigned short*)(w + off); off += (size_t)64 * 416 * 2;
    unsigned short* T1l = (unsigned short*)(w + off); off += (size_t)64 * 416 * 2;
    unsigned short* T2h = (unsigned short*)(w + off); off += (size_t)64 * 64 * 2;
    unsigned short* T2l = (unsigned short*)(w + off); off += (size_t)64 * 64 * 2;
    unsigned short* T3h = (unsigned short*)(w + off); off += (size_t)64 * 64 * 2;
    unsigned short* T3l = (unsigned short*)(w + off); off += (size_t)64 * 64 * 2;
    float* cs2 = (float*)(w + off); off += 64 * 4;
    float* cs3 = (float*)(w + off); off += 64 * 4;
    unsigned short* Ut = (unsigned short*)(w + off); off += (size_t)Bb * 64 * UTP * 2;
    float* Z = (float*)(w + off);              off += (size_t)Mrows * Hh * 4;
    float* stats = (float*)(w + off);          off += 1600 * 4;
    float* ssum1 = stats, *ssq1 = stats + 400, *ssum2 = stats + 800, *ssq2 = stats + 1200;
    float* mean1 = (float*)(w + off); off += 1600;
    float* inv1  = (float*)(w + off); off += 1600;
    float* mean2 = (float*)(w + off); off += 1600;
    float* inv2  = (float*)(w + off); off += 1600;
    float* out1  = (float*)(w + off); off += Bb * Hh * 4;
    float* out2  = (float*)(w + off); off += Bb * Hh * 4;
    float* out3  = (float*)(w + off); off += Bb * Hh * 4;

    float* ypred = (float*)d_out;
    float* x3    = (float*)d_out + 512;

    // Prep: densify adjacency (bf16 [400][416]) + split weights
    initk<<<384, 1024, 0, stream>>>(Adf, stats, Ut);
    scatAk<<<(NNZ + 255) / 256, 256, 0, stream>>>(arow, acol, aval, Adf);
    cvtAk<<<(Nn * KP + 1023) / 1024, 1024, 0, stream>>>(Adf, Adbf);
    wprep<<<192, 256, 0, stream>>>(W1, W2, W3, T1h, T1l, T2h, T2l, T3h, T3l, cs2, cs3);

    // Layer 1
    xg<FIN, false><<<Mrows / 64, 256, 0, stream>>>(x, T1h, T1l, nullptr, Ut, nullptr, nullptr);
    aggmm<true><<<Bb * 4, 256, 0, stream>>>(Adbf, Ut, b1, Z, ssum1, ssq1);
    finalize_stats<<<1, 512, 0, stream>>>(ssum1, ssq1, mean1, inv1);
    maxk<true><<<Bb, 256, 0, stream>>>(Z, mean1, inv1, out1);

    // Layer 2 (BN of layer 1 folded into GEMM epilogue)
    xg<Hh, true><<<Mrows / 64, 256, 0, stream>>>(Z, T2h, T2l, cs2, Ut, mean1, inv1);
    aggmm<true><<<Bb * 4, 256, 0, stream>>>(Adbf, Ut, b2, Z, ssum2, ssq2);
    finalize_stats<<<1, 512, 0, stream>>>(ssum2, ssq2, mean2, inv2);
    maxk<true><<<Bb, 256, 0, stream>>>(Z, mean2, inv2, out2);

    // Layer 3 (no relu / no BN) -> x3 f32 into d_out
    xg<Hh, true><<<Mrows / 64, 256, 0, stream>>>(Z, T3h, T3l, cs3, Ut, mean2, inv2);
    aggmm<false><<<Bb * 4, 256, 0, stream>>>(Adbf, Ut, b3, x3, nullptr, nullptr);
    maxk<false><<<Bb, 256, 0, stream>>>(x3, nullptr, nullptr, out3);

    // FC head
    headk<<<1, 1024, 0, stream>>>(out1, out2, out3, fc1W, fc1b, fc2W, fc2b,
                                  fc3W, fc3b, ypred);
}

// Round 8
// 377.826 us; speedup vs baseline: 1.0453x; 1.0453x over previous
//
#include <hip/hip_runtime.h>
#include <hip/hip_bf16.h>
#include <math.h>

// Problem constants
#define Bb   256
#define Nn   400
#define FIN  400
#define Hh   64
#define NNZ  16000
#define Mrows (Bb*Nn)          // 102400
#define KP   416               // dense-adj K padded to 13*32 for MFMA
#define UTP  416               // Ut node-dim stride (shorts), 16B-aligned rows
#define BH_COUNT 16384.0f      // B*H for BN3 stats

typedef unsigned int  u32x2 __attribute__((ext_vector_type(2)));
typedef unsigned int  u32x4 __attribute__((ext_vector_type(4)));
typedef __bf16        bf16x8 __attribute__((ext_vector_type(8)));
typedef float         f32x4 __attribute__((ext_vector_type(4)));

__device__ __forceinline__ unsigned int f2bf(float x) {
    unsigned int u = __builtin_bit_cast(unsigned int, x);
    return (u + 0x7FFFu + ((u >> 16) & 1u)) >> 16;   // RNE
}
__device__ __forceinline__ float bf2f(unsigned int h) {
    unsigned int u = h << 16;
    return __builtin_bit_cast(float, u);
}

// ---------------------------------------------------------------------------
// init: zero dense-A f32 accumulator, BN stats, Ut node-pad (400..415)
// ---------------------------------------------------------------------------
__global__ void initk(float* __restrict__ Adf, float* __restrict__ stats,
                      unsigned short* __restrict__ Ut) {
    int t = blockIdx.x * blockDim.x + threadIdx.x;
    if (t < Nn * KP) Adf[t] = 0.f;
    if (t < 1600) stats[t] = 0.f;   // ssum1, ssq1, ssum2, ssq2 (4 x 400)
    if (t < Bb * Hh * 16) {
        int bh = t >> 4, k = Nn + (t & 15);
        Ut[(size_t)bh * UTP + k] = 0;
    }
}

__global__ void scatAk(const int* __restrict__ rows, const int* __restrict__ cols,
                       const float* __restrict__ vals, float* __restrict__ Adf) {
    int i = blockIdx.x * blockDim.x + threadIdx.x;
    if (i < NNZ) atomicAdd(&Adf[rows[i] * KP + cols[i]], vals[i]);
}

__global__ void cvtAk(const float* __restrict__ Adf, unsigned short* __restrict__ Adbf) {
    int i = blockIdx.x * blockDim.x + threadIdx.x;
    if (i < Nn * KP) Adbf[i] = (unsigned short)f2bf(Adf[i]);
}

// ---------------------------------------------------------------------------
// W prep: split W[KT][64] -> hi/lo bf16 in B-fragment layout [col][KPAD]
// (k-major per column), plus colsum. block = one column of one W.
// ---------------------------------------------------------------------------
__global__ __launch_bounds__(256) void wprep(
        const float* __restrict__ W1, const float* __restrict__ W2,
        const float* __restrict__ W3,
        unsigned short* __restrict__ T1h, unsigned short* __restrict__ T1l,
        unsigned short* __restrict__ T2h, unsigned short* __restrict__ T2l,
        unsigned short* __restrict__ T3h, unsigned short* __restrict__ T3l,
        float* __restrict__ cs2, float* __restrict__ cs3) {
    const int w = blockIdx.x >> 6;        // 0,1,2
    const int c = blockIdx.x & 63;
    const float* W = (w == 0) ? W1 : (w == 1) ? W2 : W3;
    const int KT   = (w == 0) ? FIN : Hh;
    const int KPAD = (w == 0) ? 416 : 64;
    unsigned short* Th = (w == 0) ? T1h : (w == 1) ? T2h : T3h;
    unsigned short* Tl = (w == 0) ? T1l : (w == 1) ? T2l : T3l;

    float s = 0.f;
    for (int k = threadIdx.x; k < KPAD; k += 256) {
        float v = (k < KT) ? W[k * 64 + c] : 0.f;
        unsigned int hb = f2bf(v);
        Th[c * KPAD + k] = (unsigned short)hb;
        Tl[c * KPAD + k] = (unsigned short)f2bf(v - bf2f(hb));
        s += v;
    }
    __shared__ float red[256];
    red[threadIdx.x] = s;
    __syncthreads();
    for (int o = 128; o; o >>= 1) {
        if (threadIdx.x < o) red[threadIdx.x] += red[threadIdx.x + o];
        __syncthreads();
    }
    if (threadIdx.x == 0) {
        if (w == 1) cs2[c] = red[0];
        else if (w == 2) cs3[c] = red[0];
    }
}

// ---------------------------------------------------------------------------
// Layer-1 GEMM (split precision, LDS-free, pipelined):
//   Ut = x[M,400](f32) @ W1[400,64]  -> bf16, transposed per batch
// 4 waves x 2 M-tiles (32 rows) = 128 rows/block. 2-deep SW pipeline:
// next K-step's A(4xdwordx4) + W(8xdwordx4) issued before current compute.
// OOB note: kk>392 clamped; W-frag rows 400..415 are zero so the product
// of the clamped (wrong-position) A values is 0.
// ---------------------------------------------------------------------------
__global__ __launch_bounds__(256) void xg400(
        const float* __restrict__ A,
        const unsigned short* __restrict__ Wth,
        const unsigned short* __restrict__ Wtl,
        unsigned short* __restrict__ Ut) {
    const int tid  = threadIdx.x;
    const int wv   = tid >> 6;
    const int lane = tid & 63;
    const int cl   = lane & 15;
    const int g    = lane >> 4;
    const int m0   = blockIdx.x * 128;
    const int rowA = m0 + wv * 32 + cl;
    const int rowB = rowA + 16;

    f32x4 acc[2][4];
#pragma unroll
    for (int t2 = 0; t2 < 2; ++t2)
#pragma unroll
        for (int n = 0; n < 4; ++n) acc[t2][n] = f32x4{0.f, 0.f, 0.f, 0.f};

    auto loadA = [&](int s, float4& l0, float4& h0, float4& l1, float4& h1) {
        int kk = s * 32 + g * 8;
        int kc = kk > 392 ? 392 : kk;                 // clamp (W pad is zero)
        const float* p = &A[(size_t)rowA * FIN + kc];
        l0 = *reinterpret_cast<const float4*>(p);
        h0 = *reinterpret_cast<const float4*>(p + 4);
        const float* q = &A[(size_t)rowB * FIN + kc];
        l1 = *reinterpret_cast<const float4*>(q);
        h1 = *reinterpret_cast<const float4*>(q + 4);
    };
    auto loadW = [&](int s, u32x4* dst) {
        int kk = s * 32 + g * 8;
#pragma unroll
        for (int n = 0; n < 4; ++n) {
            dst[n]     = *reinterpret_cast<const u32x4*>(&Wth[(size_t)(n * 16 + cl) * 416 + kk]);
            dst[4 + n] = *reinterpret_cast<const u32x4*>(&Wtl[(size_t)(n * 16 + cl) * 416 + kk]);
        }
    };
    auto split = [&](const float4& lo, const float4& hi, bf16x8& ah, bf16x8& al) {
        float v0 = lo.x, v1 = lo.y, v2 = lo.z, v3 = lo.w;
        float v4 = hi.x, v5 = hi.y, v6 = hi.z, v7 = hi.w;
        unsigned h0, h1;
        u32x4 hw, lw;
        h0 = f2bf(v0); h1 = f2bf(v1);
        hw[0] = h0 | (h1 << 16);
        lw[0] = f2bf(v0 - bf2f(h0)) | (f2bf(v1 - bf2f(h1)) << 16);
        h0 = f2bf(v2); h1 = f2bf(v3);
        hw[1] = h0 | (h1 << 16);
        lw[1] = f2bf(v2 - bf2f(h0)) | (f2bf(v3 - bf2f(h1)) << 16);
        h0 = f2bf(v4); h1 = f2bf(v5);
        hw[2] = h0 | (h1 << 16);
        lw[2] = f2bf(v4 - bf2f(h0)) | (f2bf(v5 - bf2f(h1)) << 16);
        h0 = f2bf(v6); h1 = f2bf(v7);
        hw[3] = h0 | (h1 << 16);
        lw[3] = f2bf(v6 - bf2f(h0)) | (f2bf(v7 - bf2f(h1)) << 16);
        ah = __builtin_bit_cast(bf16x8, hw);
        al = __builtin_bit_cast(bf16x8, lw);
    };

    float4 cAl0, cAh0, cAl1, cAh1, nAl0, nAh0, nAl1, nAh1;
    u32x4  cW[8], nW[8];
    loadA(0, cAl0, cAh0, cAl1, cAh1);
    loadW(0, cW);

    for (int s = 0; s < 13; ++s) {
        if (s < 12) {
            loadA(s + 1, nAl0, nAh0, nAl1, nAh1);
            loadW(s + 1, nW);
        }
        bf16x8 ah0, al0, ah1, al1;
        split(cAl0, cAh0, ah0, al0);
        split(cAl1, cAh1, ah1, al1);
#pragma unroll
        for (int n = 0; n < 4; ++n) {
            bf16x8 bh = __builtin_bit_cast(bf16x8, cW[n]);
            bf16x8 bl = __builtin_bit_cast(bf16x8, cW[4 + n]);
            acc[0][n] = __builtin_amdgcn_mfma_f32_16x16x32_bf16(ah0, bh, acc[0][n], 0, 0, 0);
            acc[0][n] = __builtin_amdgcn_mfma_f32_16x16x32_bf16(ah0, bl, acc[0][n], 0, 0, 0);
            acc[0][n] = __builtin_amdgcn_mfma_f32_16x16x32_bf16(al0, bh, acc[0][n], 0, 0, 0);
            acc[1][n] = __builtin_amdgcn_mfma_f32_16x16x32_bf16(ah1, bh, acc[1][n], 0, 0, 0);
            acc[1][n] = __builtin_amdgcn_mfma_f32_16x16x32_bf16(ah1, bl, acc[1][n], 0, 0, 0);
            acc[1][n] = __builtin_amdgcn_mfma_f32_16x16x32_bf16(al1, bh, acc[1][n], 0, 0, 0);
        }
        if (s < 12) {
            cAl0 = nAl0; cAh0 = nAh0; cAl1 = nAl1; cAh1 = nAh1;
#pragma unroll
            for (int j = 0; j < 8; ++j) cW[j] = nW[j];
        }
    }

#pragma unroll
    for (int t2 = 0; t2 < 2; ++t2) {
        const int row0  = m0 + wv * 32 + t2 * 16 + g * 4;
        const int b     = row0 / Nn;
        const int node0 = row0 - b * Nn;
#pragma unroll
        for (int n = 0; n < 4; ++n) {
            const int col = n * 16 + cl;
            u32x2 pk;
            pk[0] = f2bf(acc[t2][n][0]) | (f2bf(acc[t2][n][1]) << 16);
            pk[1] = f2bf(acc[t2][n][2]) | (f2bf(acc[t2][n][3]) << 16);
            *reinterpret_cast<u32x2*>(&Ut[((size_t)b * 64 + col) * UTP + node0]) = pk;
        }
    }
}

// ---------------------------------------------------------------------------
// Layers 2/3 GEMM (split precision, LDS-free, R6-proven):
//   Ut = Z[M,64](f32) @ W[64,64] with A-side BN affine folded via colsum:
//   C = inv[r]*(Z@W - mean[r]*colsum(W)), r = row % 400
// ---------------------------------------------------------------------------
__global__ __launch_bounds__(256) void xg64(
        const float* __restrict__ A,
        const unsigned short* __restrict__ Wth,
        const unsigned short* __restrict__ Wtl,
        const float* __restrict__ csW,
        unsigned short* __restrict__ Ut,
        const float* __restrict__ mean, const float* __restrict__ inv) {
    const int tid  = threadIdx.x;
    const int wv   = tid >> 6;
    const int lane = tid & 63;
    const int cl   = lane & 15;
    const int g    = lane >> 4;
    const int m0   = blockIdx.x * 64;
    const int arow = m0 + wv * 16 + cl;

    f32x4 acc[4];
#pragma unroll
    for (int n = 0; n < 4; ++n) acc[n] = f32x4{0.f, 0.f, 0.f, 0.f};

#pragma unroll
    for (int s = 0; s < 2; ++s) {
        const int kk = s * 32 + g * 8;
        const float* p = &A[(size_t)arow * 64 + kk];
        float4 lo = *reinterpret_cast<const float4*>(p);
        float4 hi = *reinterpret_cast<const float4*>(p + 4);
        float av[8] = {lo.x, lo.y, lo.z, lo.w, hi.x, hi.y, hi.z, hi.w};
        u32x4 ahw, alw;
#pragma unroll
        for (int j = 0; j < 4; ++j) {
            unsigned int h0 = f2bf(av[2 * j]);
            unsigned int h1 = f2bf(av[2 * j + 1]);
            unsigned int l0 = f2bf(av[2 * j]     - bf2f(h0));
            unsigned int l1 = f2bf(av[2 * j + 1] - bf2f(h1));
            ahw[j] = h0 | (h1 << 16);
            alw[j] = l0 | (l1 << 16);
        }
        bf16x8 ah = __builtin_bit_cast(bf16x8, ahw);
        bf16x8 al = __builtin_bit_cast(bf16x8, alw);
#pragma unroll
        for (int n = 0; n < 4; ++n) {
            u32x4 bhw = *reinterpret_cast<const u32x4*>(&Wth[(size_t)(n * 16 + cl) * 64 + kk]);
            u32x4 blw = *reinterpret_cast<const u32x4*>(&Wtl[(size_t)(n * 16 + cl) * 64 + kk]);
            bf16x8 bh = __builtin_bit_cast(bf16x8, bhw);
            bf16x8 bl = __builtin_bit_cast(bf16x8, blw);
            acc[n] = __builtin_amdgcn_mfma_f32_16x16x32_bf16(ah, bh, acc[n], 0, 0, 0);
            acc[n] = __builtin_amdgcn_mfma_f32_16x16x32_bf16(ah, bl, acc[n], 0, 0, 0);
            acc[n] = __builtin_amdgcn_mfma_f32_16x16x32_bf16(al, bh, acc[n], 0, 0, 0);
        }
    }

    // epilogue: 4 consecutive rows (one batch), packed 8B transposed store
    const int row0  = m0 + wv * 16 + g * 4;
    const int b     = row0 / Nn;
    const int node0 = row0 - b * Nn;
    float mm[4], iv[4];
#pragma unroll
    for (int r = 0; r < 4; ++r) { mm[r] = mean[node0 + r]; iv[r] = inv[node0 + r]; }
#pragma unroll
    for (int n = 0; n < 4; ++n) {
        const int col = n * 16 + cl;
        const float cw = csW[col];
        float y[4];
#pragma unroll
        for (int r = 0; r < 4; ++r)
            y[r] = iv[r] * (acc[n][r] - mm[r] * cw);
        u32x2 pk;
        pk[0] = f2bf(y[0]) | (f2bf(y[1]) << 16);
        pk[1] = f2bf(y[2]) | (f2bf(y[3]) << 16);
        *reinterpret_cast<u32x2*>(&Ut[((size_t)b * 64 + col) * UTP + node0]) = pk;
    }
}

// ---------------------------------------------------------------------------
// Dense MFMA aggregation, LDS-free: Z[b] = normalize(Adj @ U[b] + bias)
//   STATS: + relu + BN3 stat atomics.
// 4 blocks per batch, 256 threads = 4 waves.
// ---------------------------------------------------------------------------
template <bool STATS>
__global__ __launch_bounds__(256) void aggmm(
        const unsigned short* __restrict__ Ad,   // [400][416] bf16 bits
        const unsigned short* __restrict__ Ut,   // [B*64][416] bf16 bits
        const float* __restrict__ bias,
        float* __restrict__ Zout,                // [B*400][64] f32
        float* __restrict__ ssum, float* __restrict__ ssq) {
    const int b    = blockIdx.x >> 2;
    const int q    = blockIdx.x & 3;
    const int tid  = threadIdx.x;
    const int lane = tid & 63;
    const int wv   = tid >> 6;
    const int cl   = lane & 15;
    const int g    = lane >> 4;
    const unsigned short* __restrict__ Ub = Ut + (size_t)b * 64 * UTP;

    f32x4 acc[2][4];
#pragma unroll
    for (int i = 0; i < 2; ++i)
#pragma unroll
        for (int n = 0; n < 4; ++n) acc[i][n] = f32x4{0.f, 0.f, 0.f, 0.f};

    for (int k0 = 0; k0 < KP; k0 += 32) {
        const int kk = k0 + g * 8;
        bf16x8 bf[4];
#pragma unroll
        for (int n = 0; n < 4; ++n) {
            u32x4 w = *reinterpret_cast<const u32x4*>(&Ub[(size_t)(n * 16 + cl) * UTP + kk]);
            bf[n] = __builtin_bit_cast(bf16x8, w);
        }
#pragma unroll
        for (int i = 0; i < 2; ++i) {
            const int t = q + 4 * wv + 16 * i;
            if (t < 25) {
                const int row = t * 16 + cl;
                u32x4 ar = *reinterpret_cast<const u32x4*>(&Ad[(size_t)row * KP + kk]);
                bf16x8 af = __builtin_bit_cast(bf16x8, ar);
#pragma unroll
                for (int n = 0; n < 4; ++n)
                    acc[i][n] = __builtin_amdgcn_mfma_f32_16x16x32_bf16(
                        af, bf[n], acc[i][n], 0, 0, 0);
            }
        }
    }

    float bv[4];
#pragma unroll
    for (int n = 0; n < 4; ++n) bv[n] = bias[n * 16 + cl];

#pragma unroll
    for (int i = 0; i < 2; ++i) {
        const int t = q + 4 * wv + 16 * i;
        if (t < 25) {
            float y[4][4];
#pragma unroll
            for (int n = 0; n < 4; ++n)
#pragma unroll
                for (int r = 0; r < 4; ++r) y[n][r] = acc[i][n][r] + bv[n];

            float pss[4];
#pragma unroll
            for (int r = 0; r < 4; ++r)
                pss[r] = y[0][r]*y[0][r] + y[1][r]*y[1][r] +
                         y[2][r]*y[2][r] + y[3][r]*y[3][r];
#pragma unroll
            for (int m = 1; m < 16; m <<= 1)
#pragma unroll
                for (int r = 0; r < 4; ++r) pss[r] += __shfl_xor(pss[r], m);

            float rin[4];
#pragma unroll
            for (int r = 0; r < 4; ++r)
                rin[r] = 1.f / fmaxf(sqrtf(pss[r]), 1e-12f);

#pragma unroll
            for (int n = 0; n < 4; ++n)
#pragma unroll
                for (int r = 0; r < 4; ++r) {
                    float z = y[n][r] * rin[r];
                    if (STATS) z = fmaxf(z, 0.f);
                    y[n][r] = z;
                    const int row = t * 16 + g * 4 + r;
                    Zout[((size_t)b * Nn + row) * Hh + n * 16 + cl] = z;
                }

            if (STATS) {
                float s1[4], s2[4];
#pragma unroll
                for (int r = 0; r < 4; ++r) {
                    s1[r] = y[0][r] + y[1][r] + y[2][r] + y[3][r];
                    s2[r] = y[0][r]*y[0][r] + y[1][r]*y[1][r] +
                            y[2][r]*y[2][r] + y[3][r]*y[3][r];
                }
#pragma unroll
                for (int m = 1; m < 16; m <<= 1)
#pragma unroll
                    for (int r = 0; r < 4; ++r) {
                        s1[r] += __shfl_xor(s1[r], m);
                        s2[r] += __shfl_xor(s2[r], m);
                    }
                if (cl == 0) {
#pragma unroll
                    for (int r = 0; r < 4; ++r) {
                        const int row = t * 16 + g * 4 + r;
                        atomicAdd(&ssum[row], s1[r]);
                        atomicAdd(&ssq[row],  s2[r]);
                    }
                }
            }
        }
    }
}

__global__ void finalize_stats(const float* __restrict__ ssum,
                               const float* __restrict__ ssq,
                               float* __restrict__ mean, float* __restrict__ inv) {
    int r = threadIdx.x;
    if (r < Nn) {
        float m = ssum[r] * (1.0f / BH_COUNT);
        float v = ssq[r] * (1.0f / BH_COUNT) - m * m;
        mean[r] = m;
        inv[r]  = rsqrtf(v + 1e-5f);
    }
}

// ---------------------------------------------------------------------------
// out[b,h] = max_r affine(Z[b,r,h])   (AFF = BN3; else identity)
// ---------------------------------------------------------------------------
template <bool AFF>
__global__ __launch_bounds__(256) void maxk(
        const float* __restrict__ Z, const float* __restrict__ mean,
        const float* __restrict__ inv, float* __restrict__ out) {
    __shared__ float red[4][64];
    const int b  = blockIdx.x;
    const int h  = threadIdx.x & 63;
    const int rg = threadIdx.x >> 6;
    float best = -3.4e38f;
    for (int r = rg; r < Nn; r += 4) {
        float v = Z[((size_t)b * Nn + r) * Hh + h];
        if (AFF) v = (v - mean[r]) * inv[r];
        best = fmaxf(best, v);
    }
    red[rg][h] = best;
    __syncthreads();
    if (threadIdx.x < 64) {
        float m = fmaxf(fmaxf(red[0][threadIdx.x], red[1][threadIdx.x]),
                        fmaxf(red[2][threadIdx.x], red[3][threadIdx.x]));
        out[b * Hh + threadIdx.x] = m;
    }
}

// ---------------------------------------------------------------------------
// FC head: h=[out1|out2|out3] (256x192) -> fc1+relu+bn2 -> fc2+relu+bn2 -> fc3
// ---------------------------------------------------------------------------
__global__ __launch_bounds__(1024) void headk(
        const float* __restrict__ out1, const float* __restrict__ out2,
        const float* __restrict__ out3,
        const float* __restrict__ W1f, const float* __restrict__ b1f,
        const float* __restrict__ W2f, const float* __restrict__ b2f,
        const float* __restrict__ W3f, const float* __restrict__ b3f,
        float* __restrict__ ypred) {
    __shared__ float gA[256][64];     // 64 KB activations
    __shared__ float w1s[192 * 64];   // 48 KB
    __shared__ float w2s[64 * 64];    // 16 KB
    __shared__ float mS[64], iS[64];
    const int t = threadIdx.x;
    const int r = t >> 2, q = t & 3;

    for (int i = t; i < 192 * 64; i += 1024) w1s[i] = W1f[i];
    for (int i = t; i < 64 * 64; i += 1024) w2s[i] = W2f[i];
    __syncthreads();

    float acc[16];
#pragma unroll
    for (int j = 0; j < 16; ++j) acc[j] = b1f[q * 16 + j];
    for (int k = 0; k < 192; ++k) {
        float hv = (k < 64) ? out1[r * 64 + k]
                 : (k < 128) ? out2[r * 64 + (k - 64)]
                             : out3[r * 64 + (k - 128)];
#pragma unroll
        for (int j = 0; j < 16; ++j) acc[j] += hv * w1s[k * 64 + q * 16 + j];
    }
#pragma unroll
    for (int j = 0; j < 16; ++j) gA[r][q * 16 + j] = fmaxf(acc[j], 0.f);
    __syncthreads();

    if (t < 64) {
        float s = 0.f, s2 = 0.f;
        for (int rr = 0; rr < 256; ++rr) { float v = gA[rr][t]; s += v; s2 += v * v; }
        float m = s * (1.f / 256.f);
        float var = s2 * (1.f / 256.f) - m * m;
        mS[t] = m;
        iS[t] = rsqrtf(var + 1e-5f);
    }
    __syncthreads();

#pragma unroll
    for (int j = 0; j < 16; ++j) acc[j] = b2f[q * 16 + j];
#pragma unroll
    for (int k = 0; k < 64; ++k) {
        float gn = (gA[r][k] - mS[k]) * iS[k];
#pragma unroll
        for (int j = 0; j < 16; ++j) acc[j] += gn * w2s[k * 64 + q * 16 + j];
    }
    __syncthreads();
#pragma unroll
    for (int j = 0; j < 16; ++j) gA[r][q * 16 + j] = fmaxf(acc[j], 0.f);
    __syncthreads();

    if (t < 64) {
        float s = 0.f, s2 = 0.f;
        for (int rr = 0; rr < 256; ++rr) { float v = gA[rr][t]; s += v; s2 += v * v; }
        float m = s * (1.f / 256.f);
        float var = s2 * (1.f / 256.f) - m * m;
        mS[t] = m;
        iS[t] = rsqrtf(var + 1e-5f);
    }
    __syncthreads();

    if (q < 2) {
        float a = b3f[q];
#pragma unroll
        for (int k = 0; k < 64; ++k) {
            float gn = (gA[r][k] - mS[k]) * iS[k];
            a += gn * W3f[k * 2 + q];
        }
        ypred[r * 2 + q] = a;
    }
}

// ---------------------------------------------------------------------------
extern "C" void kernel_launch(void* const* d_in, const int* in_sizes, int n_in,
                              void* d_out, int out_size, void* d_ws, size_t ws_size,
                              hipStream_t stream) {
    const float* x    = (const float*)d_in[0];
    const int*   arow = (const int*)d_in[1];
    const int*   acol = (const int*)d_in[2];
    const float* aval = (const float*)d_in[3];
    const float* W1 = (const float*)d_in[4];
    const float* b1 = (const float*)d_in[5];
    const float* W2 = (const float*)d_in[6];
    const float* b2 = (const float*)d_in[7];
    const float* W3 = (const float*)d_in[8];
    const float* b3 = (const float*)d_in[9];
    const float* fc1W = (const float*)d_in[10];
    const float* fc1b = (const float*)d_in[11];
    const float* fc2W = (const float*)d_in[12];
    const float* fc2b = (const float*)d_in[13];
    const float* fc3W = (const float*)d_in[14];
    const float* fc3b = (const float*)d_in[15];

    char* w = (char*)d_ws;
    size_t off = 0;
    float* Adf = (float*)(w + off);            off += (size_t)Nn * KP * 4;
    unsigned short* Adbf = (unsigned short*)(w + off); off += (size_t)Nn * KP * 2;
    unsigned short* T1h = (unsigned short*)(w + off); off += (size_t)64 * 416 * 2;
    unsigned short* T1l = (unsigned short*)(w + off); off += (size_t)64 * 416 * 2;
    unsigned short* T2h = (unsigned short*)(w + off); off += (size_t)64 * 64 * 2;
    unsigned short* T2l = (unsigned short*)(w + off); off += (size_t)64 * 64 * 2;
    unsigned short* T3h = (unsigned short*)(w + off); off += (size_t)64 * 64 * 2;
    unsigned short* T3l = (unsigned short*)(w + off); off += (size_t)64 * 64 * 2;
    float* cs2 = (float*)(w + off); off += 64 * 4;
    float* cs3 = (float*)(w + off); off += 64 * 4;
    unsigned short* Ut = (unsigned short*)(w + off); off += (size_t)Bb * 64 * UTP * 2;
    float* Z = (float*)(w + off);              off += (size_t)Mrows * Hh * 4;
    float* stats = (float*)(w + off);          off += 1600 * 4;
    float* ssum1 = stats, *ssq1 = stats + 400, *ssum2 = stats + 800, *ssq2 = stats + 1200;
    float* mean1 = (float*)(w + off); off += 1600;
    float* inv1  = (float*)(w + off); off += 1600;
    float* mean2 = (float*)(w + off); off += 1600;
    float* inv2  = (float*)(w + off); off += 1600;
    float* out1  = (float*)(w + off); off += Bb * Hh * 4;
    float* out2  = (float*)(w + off); off += Bb * Hh * 4;
    float* out3  = (float*)(w + off); off += Bb * Hh * 4;

    float* ypred = (float*)d_out;
    float* x3    = (float*)d_out + 512;

    // Prep: densify adjacency (bf16 [400][416]) + split weights
    initk<<<384, 1024, 0, stream>>>(Adf, stats, Ut);
    scatAk<<<(NNZ + 255) / 256, 256, 0, stream>>>(arow, acol, aval, Adf);
    cvtAk<<<(Nn * KP + 1023) / 1024, 1024, 0, stream>>>(Adf, Adbf);
    wprep<<<192, 256, 0, stream>>>(W1, W2, W3, T1h, T1l, T2h, T2l, T3h, T3l, cs2, cs3);

    // Layer 1 (pipelined 2-tile GEMM)
    xg400<<<Mrows / 128, 256, 0, stream>>>(x, T1h, T1l, Ut);
    aggmm<true><<<Bb * 4, 256, 0, stream>>>(Adbf, Ut, b1, Z, ssum1, ssq1);
    finalize_stats<<<1, 512, 0, stream>>>(ssum1, ssq1, mean1, inv1);
    maxk<true><<<Bb, 256, 0, stream>>>(Z, mean1, inv1, out1);

    // Layer 2 (BN1 folded via colsum epilogue)
    xg64<<<Mrows / 64, 256, 0, stream>>>(Z, T2h, T2l, cs2, Ut, mean1, inv1);
    aggmm<true><<<Bb * 4, 256, 0, stream>>>(Adbf, Ut, b2, Z, ssum2, ssq2);
    finalize_stats<<<1, 512, 0, stream>>>(ssum2, ssq2, mean2, inv2);
    maxk<true><<<Bb, 256, 0, stream>>>(Z, mean2, inv2, out2);

    // Layer 3 (BN2 folded) -> x3 f32 into d_out
    xg64<<<Mrows / 64, 256, 0, stream>>>(Z, T3h, T3l, cs3, Ut, mean2, inv2);
    aggmm<false><<<Bb * 4, 256, 0, stream>>>(Adbf, Ut, b3, x3, nullptr, nullptr);
    maxk<false><<<Bb, 256, 0, stream>>>(x3, nullptr, nullptr, out3);

    // FC head
    headk<<<1, 1024, 0, stream>>>(out1, out2, out3, fc1W, fc1b, fc2W, fc2b,
                                  fc3W, fc3b, ypred);
}

// Round 9
// 318.356 us; speedup vs baseline: 1.2406x; 1.1868x over previous
//
#include <hip/hip_runtime.h>
#include <hip/hip_bf16.h>
#include <math.h>

// Problem constants
#define Bb   256
#define Nn   400
#define FIN  400
#define Hh   64
#define NNZ  16000
#define Mrows (Bb*Nn)          // 102400
#define KP   416               // dense-adj K padded to 13*32 for MFMA
#define UTP  416               // Ut node-dim stride (shorts), 16B-aligned rows
#define BH_COUNT 16384.0f      // B*H for BN3 stats

typedef unsigned int  u32x2 __attribute__((ext_vector_type(2)));
typedef unsigned int  u32x4 __attribute__((ext_vector_type(4)));
typedef __bf16        bf16x8 __attribute__((ext_vector_type(8)));
typedef float         f32x4 __attribute__((ext_vector_type(4)));

__device__ __forceinline__ unsigned int f2bf(float x) {
    unsigned int u = __builtin_bit_cast(unsigned int, x);
    return (u + 0x7FFFu + ((u >> 16) & 1u)) >> 16;   // RNE
}
__device__ __forceinline__ float bf2f(unsigned int h) {
    unsigned int u = h << 16;
    return __builtin_bit_cast(float, u);
}

// ---------------------------------------------------------------------------
// init: zero dense-A f32 accumulator, BN stats, Ut node-pad (400..415)
// ---------------------------------------------------------------------------
__global__ void initk(float* __restrict__ Adf, float* __restrict__ stats,
                      unsigned short* __restrict__ Ut) {
    int t = blockIdx.x * blockDim.x + threadIdx.x;
    if (t < Nn * KP) Adf[t] = 0.f;
    if (t < 1600) stats[t] = 0.f;   // ssum1, ssq1, ssum2, ssq2 (4 x 400)
    if (t < Bb * Hh * 16) {
        int bh = t >> 4, k = Nn + (t & 15);
        Ut[(size_t)bh * UTP + k] = 0;
    }
}

__global__ void scatAk(const int* __restrict__ rows, const int* __restrict__ cols,
                       const float* __restrict__ vals, float* __restrict__ Adf) {
    int i = blockIdx.x * blockDim.x + threadIdx.x;
    if (i < NNZ) atomicAdd(&Adf[rows[i] * KP + cols[i]], vals[i]);
}

__global__ void cvtAk(const float* __restrict__ Adf, unsigned short* __restrict__ Adbf) {
    int i = blockIdx.x * blockDim.x + threadIdx.x;
    if (i < Nn * KP) Adbf[i] = (unsigned short)f2bf(Adf[i]);
}

// ---------------------------------------------------------------------------
// W prep: split W[KT][64] -> hi/lo bf16 in B-fragment layout [col][KPAD]
// ---------------------------------------------------------------------------
__global__ __launch_bounds__(256) void wprep(
        const float* __restrict__ W1, const float* __restrict__ W2,
        const float* __restrict__ W3,
        unsigned short* __restrict__ T1h, unsigned short* __restrict__ T1l,
        unsigned short* __restrict__ T2h, unsigned short* __restrict__ T2l,
        unsigned short* __restrict__ T3h, unsigned short* __restrict__ T3l) {
    const int w = blockIdx.x >> 6;        // 0,1,2
    const int c = blockIdx.x & 63;
    const float* W = (w == 0) ? W1 : (w == 1) ? W2 : W3;
    const int KT   = (w == 0) ? FIN : Hh;
    const int KPAD = (w == 0) ? 416 : 64;
    unsigned short* Th = (w == 0) ? T1h : (w == 1) ? T2h : T3h;
    unsigned short* Tl = (w == 0) ? T1l : (w == 1) ? T2l : T3l;

    for (int k = threadIdx.x; k < KPAD; k += 256) {
        float v = (k < KT) ? W[k * 64 + c] : 0.f;
        unsigned int hb = f2bf(v);
        Th[c * KPAD + k] = (unsigned short)hb;
        Tl[c * KPAD + k] = (unsigned short)f2bf(v - bf2f(hb));
    }
}

// ---------------------------------------------------------------------------
// Layer-1 GEMM (split precision, LDS-free, pipelined) — R8-proven:
//   Ut = x[M,400](f32) @ W1[400,64]  -> bf16, transposed per batch
// ---------------------------------------------------------------------------
__global__ __launch_bounds__(256) void xg400(
        const float* __restrict__ A,
        const unsigned short* __restrict__ Wth,
        const unsigned short* __restrict__ Wtl,
        unsigned short* __restrict__ Ut) {
    const int tid  = threadIdx.x;
    const int wv   = tid >> 6;
    const int lane = tid & 63;
    const int cl   = lane & 15;
    const int g    = lane >> 4;
    const int m0   = blockIdx.x * 128;
    const int rowA = m0 + wv * 32 + cl;
    const int rowB = rowA + 16;

    f32x4 acc[2][4];
#pragma unroll
    for (int t2 = 0; t2 < 2; ++t2)
#pragma unroll
        for (int n = 0; n < 4; ++n) acc[t2][n] = f32x4{0.f, 0.f, 0.f, 0.f};

    auto loadA = [&](int s, float4& l0, float4& h0, float4& l1, float4& h1) {
        int kk = s * 32 + g * 8;
        int kc = kk > 392 ? 392 : kk;                 // clamp (W pad is zero)
        const float* p = &A[(size_t)rowA * FIN + kc];
        l0 = *reinterpret_cast<const float4*>(p);
        h0 = *reinterpret_cast<const float4*>(p + 4);
        const float* q = &A[(size_t)rowB * FIN + kc];
        l1 = *reinterpret_cast<const float4*>(q);
        h1 = *reinterpret_cast<const float4*>(q + 4);
    };
    auto loadW = [&](int s, u32x4* dst) {
        int kk = s * 32 + g * 8;
#pragma unroll
        for (int n = 0; n < 4; ++n) {
            dst[n]     = *reinterpret_cast<const u32x4*>(&Wth[(size_t)(n * 16 + cl) * 416 + kk]);
            dst[4 + n] = *reinterpret_cast<const u32x4*>(&Wtl[(size_t)(n * 16 + cl) * 416 + kk]);
        }
    };
    auto split = [&](const float4& lo, const float4& hi, bf16x8& ah, bf16x8& al) {
        float v0 = lo.x, v1 = lo.y, v2 = lo.z, v3 = lo.w;
        float v4 = hi.x, v5 = hi.y, v6 = hi.z, v7 = hi.w;
        unsigned h0, h1;
        u32x4 hw, lw;
        h0 = f2bf(v0); h1 = f2bf(v1);
        hw[0] = h0 | (h1 << 16);
        lw[0] = f2bf(v0 - bf2f(h0)) | (f2bf(v1 - bf2f(h1)) << 16);
        h0 = f2bf(v2); h1 = f2bf(v3);
        hw[1] = h0 | (h1 << 16);
        lw[1] = f2bf(v2 - bf2f(h0)) | (f2bf(v3 - bf2f(h1)) << 16);
        h0 = f2bf(v4); h1 = f2bf(v5);
        hw[2] = h0 | (h1 << 16);
        lw[2] = f2bf(v4 - bf2f(h0)) | (f2bf(v5 - bf2f(h1)) << 16);
        h0 = f2bf(v6); h1 = f2bf(v7);
        hw[3] = h0 | (h1 << 16);
        lw[3] = f2bf(v6 - bf2f(h0)) | (f2bf(v7 - bf2f(h1)) << 16);
        ah = __builtin_bit_cast(bf16x8, hw);
        al = __builtin_bit_cast(bf16x8, lw);
    };

    float4 cAl0, cAh0, cAl1, cAh1, nAl0, nAh0, nAl1, nAh1;
    u32x4  cW[8], nW[8];
    loadA(0, cAl0, cAh0, cAl1, cAh1);
    loadW(0, cW);

    for (int s = 0; s < 13; ++s) {
        if (s < 12) {
            loadA(s + 1, nAl0, nAh0, nAl1, nAh1);
            loadW(s + 1, nW);
        }
        bf16x8 ah0, al0, ah1, al1;
        split(cAl0, cAh0, ah0, al0);
        split(cAl1, cAh1, ah1, al1);
#pragma unroll
        for (int n = 0; n < 4; ++n) {
            bf16x8 bh = __builtin_bit_cast(bf16x8, cW[n]);
            bf16x8 bl = __builtin_bit_cast(bf16x8, cW[4 + n]);
            acc[0][n] = __builtin_amdgcn_mfma_f32_16x16x32_bf16(ah0, bh, acc[0][n], 0, 0, 0);
            acc[0][n] = __builtin_amdgcn_mfma_f32_16x16x32_bf16(ah0, bl, acc[0][n], 0, 0, 0);
            acc[0][n] = __builtin_amdgcn_mfma_f32_16x16x32_bf16(al0, bh, acc[0][n], 0, 0, 0);
            acc[1][n] = __builtin_amdgcn_mfma_f32_16x16x32_bf16(ah1, bh, acc[1][n], 0, 0, 0);
            acc[1][n] = __builtin_amdgcn_mfma_f32_16x16x32_bf16(ah1, bl, acc[1][n], 0, 0, 0);
            acc[1][n] = __builtin_amdgcn_mfma_f32_16x16x32_bf16(al1, bh, acc[1][n], 0, 0, 0);
        }
        if (s < 12) {
            cAl0 = nAl0; cAh0 = nAh0; cAl1 = nAl1; cAh1 = nAh1;
#pragma unroll
            for (int j = 0; j < 8; ++j) cW[j] = nW[j];
        }
    }

#pragma unroll
    for (int t2 = 0; t2 < 2; ++t2) {
        const int row0  = m0 + wv * 32 + t2 * 16 + g * 4;
        const int b     = row0 / Nn;
        const int node0 = row0 - b * Nn;
#pragma unroll
        for (int n = 0; n < 4; ++n) {
            const int col = n * 16 + cl;
            u32x2 pk;
            pk[0] = f2bf(acc[t2][n][0]) | (f2bf(acc[t2][n][1]) << 16);
            pk[1] = f2bf(acc[t2][n][2]) | (f2bf(acc[t2][n][3]) << 16);
            *reinterpret_cast<u32x2*>(&Ut[((size_t)b * 64 + col) * UTP + node0]) = pk;
        }
    }
}

// ---------------------------------------------------------------------------
// Layers 2/3: block = ONE BATCH (grid 256, 8 waves). Per tile t=wv+8i (<25):
//   za = (Z[b,node] - mean[node]) * inv[node]     (elementwise BN == x1/x2)
//   Ut[b] += za @ W (split-precision MFMA, bf16 transposed out)
//   outmax[b,h] = max over nodes of za            (block-local, LDS reduce)
// No atomics, no cross-block state.
// ---------------------------------------------------------------------------
__global__ __launch_bounds__(512) void xgb(
        const float* __restrict__ Z,             // [Mrows][64] f32
        const unsigned short* __restrict__ Wth,  // [64][64] frag layout
        const unsigned short* __restrict__ Wtl,
        const float* __restrict__ mean, const float* __restrict__ inv,
        unsigned short* __restrict__ Ut,
        float* __restrict__ outmax) {            // [B][64]
    __shared__ float smax[8][64];
    const int b    = blockIdx.x;
    const int tid  = threadIdx.x;
    const int wv   = tid >> 6;
    const int lane = tid & 63;
    const int cl   = lane & 15;
    const int g    = lane >> 4;

    float vmax[16];
#pragma unroll
    for (int j = 0; j < 16; ++j) vmax[j] = -3.4e38f;

    for (int i = 0; i < 4; ++i) {
        const int t = wv + 8 * i;
        if (t < 25) {
            const int node = t * 16 + cl;
            const float mm = mean[node], iv = inv[node];

            float za[16];
#pragma unroll
            for (int s = 0; s < 2; ++s) {
                const float* p = &Z[((size_t)b * Nn + node) * 64 + s * 32 + g * 8];
                float4 lo = *reinterpret_cast<const float4*>(p);
                float4 hi = *reinterpret_cast<const float4*>(p + 4);
                za[s * 8 + 0] = (lo.x - mm) * iv;
                za[s * 8 + 1] = (lo.y - mm) * iv;
                za[s * 8 + 2] = (lo.z - mm) * iv;
                za[s * 8 + 3] = (lo.w - mm) * iv;
                za[s * 8 + 4] = (hi.x - mm) * iv;
                za[s * 8 + 5] = (hi.y - mm) * iv;
                za[s * 8 + 6] = (hi.z - mm) * iv;
                za[s * 8 + 7] = (hi.w - mm) * iv;
            }
#pragma unroll
            for (int j = 0; j < 16; ++j) vmax[j] = fmaxf(vmax[j], za[j]);

            f32x4 acc[4];
#pragma unroll
            for (int n = 0; n < 4; ++n) acc[n] = f32x4{0.f, 0.f, 0.f, 0.f};

#pragma unroll
            for (int s = 0; s < 2; ++s) {
                u32x4 hw, lw;
#pragma unroll
                for (int j = 0; j < 4; ++j) {
                    unsigned h0 = f2bf(za[s * 8 + 2 * j]);
                    unsigned h1 = f2bf(za[s * 8 + 2 * j + 1]);
                    hw[j] = h0 | (h1 << 16);
                    lw[j] = f2bf(za[s * 8 + 2 * j] - bf2f(h0)) |
                            (f2bf(za[s * 8 + 2 * j + 1] - bf2f(h1)) << 16);
                }
                bf16x8 ah = __builtin_bit_cast(bf16x8, hw);
                bf16x8 al = __builtin_bit_cast(bf16x8, lw);
                const int kk = s * 32 + g * 8;
#pragma unroll
                for (int n = 0; n < 4; ++n) {
                    u32x4 bhw = *reinterpret_cast<const u32x4*>(&Wth[(size_t)(n * 16 + cl) * 64 + kk]);
                    u32x4 blw = *reinterpret_cast<const u32x4*>(&Wtl[(size_t)(n * 16 + cl) * 64 + kk]);
                    bf16x8 bh = __builtin_bit_cast(bf16x8, bhw);
                    bf16x8 bl = __builtin_bit_cast(bf16x8, blw);
                    acc[n] = __builtin_amdgcn_mfma_f32_16x16x32_bf16(ah, bh, acc[n], 0, 0, 0);
                    acc[n] = __builtin_amdgcn_mfma_f32_16x16x32_bf16(ah, bl, acc[n], 0, 0, 0);
                    acc[n] = __builtin_amdgcn_mfma_f32_16x16x32_bf16(al, bh, acc[n], 0, 0, 0);
                }
            }

            const int node0 = t * 16 + g * 4;
#pragma unroll
            for (int n = 0; n < 4; ++n) {
                const int col = n * 16 + cl;
                u32x2 pk;
                pk[0] = f2bf(acc[n][0]) | (f2bf(acc[n][1]) << 16);
                pk[1] = f2bf(acc[n][2]) | (f2bf(acc[n][3]) << 16);
                *reinterpret_cast<u32x2*>(&Ut[((size_t)b * 64 + col) * UTP + node0]) = pk;
            }
        }
    }

    // reduce vmax over cl (rows) -> per (g, j) column max; write LDS; block max
#pragma unroll
    for (int m = 1; m < 16; m <<= 1)
#pragma unroll
        for (int j = 0; j < 16; ++j)
            vmax[j] = fmaxf(vmax[j], __shfl_xor(vmax[j], m));
    if (cl == 0) {
#pragma unroll
        for (int j = 0; j < 16; ++j) {
            const int h = 32 * (j >> 3) + g * 8 + (j & 7);
            smax[wv][h] = vmax[j];
        }
    }
    __syncthreads();
    if (tid < 64) {
        float m = smax[0][tid];
#pragma unroll
        for (int w = 1; w < 8; ++w) m = fmaxf(m, smax[w][tid]);
        outmax[b * 64 + tid] = m;
    }
}

// ---------------------------------------------------------------------------
// Dense MFMA aggregation, LDS-free: Z[b] = normalize(Adj @ U[b] + bias)
//   STATS: + relu + BN3 stat atomics.  !STATS: per-block partial col-max.
// 4 blocks per batch, 256 threads = 4 waves.
// ---------------------------------------------------------------------------
template <bool STATS>
__global__ __launch_bounds__(256) void aggmm(
        const unsigned short* __restrict__ Ad,   // [400][416] bf16 bits
        const unsigned short* __restrict__ Ut,   // [B*64][416] bf16 bits
        const float* __restrict__ bias,
        float* __restrict__ Zout,                // [B*400][64] f32
        float* __restrict__ ssum, float* __restrict__ ssq,
        float* __restrict__ pmaxq) {             // [B*4][64] (only !STATS)
    const int b    = blockIdx.x >> 2;
    const int q    = blockIdx.x & 3;
    const int tid  = threadIdx.x;
    const int lane = tid & 63;
    const int wv   = tid >> 6;
    const int cl   = lane & 15;
    const int g    = lane >> 4;
    const unsigned short* __restrict__ Ub = Ut + (size_t)b * 64 * UTP;

    f32x4 acc[2][4];
#pragma unroll
    for (int i = 0; i < 2; ++i)
#pragma unroll
        for (int n = 0; n < 4; ++n) acc[i][n] = f32x4{0.f, 0.f, 0.f, 0.f};

    for (int k0 = 0; k0 < KP; k0 += 32) {
        const int kk = k0 + g * 8;
        bf16x8 bf[4];
#pragma unroll
        for (int n = 0; n < 4; ++n) {
            u32x4 w = *reinterpret_cast<const u32x4*>(&Ub[(size_t)(n * 16 + cl) * UTP + kk]);
            bf[n] = __builtin_bit_cast(bf16x8, w);
        }
#pragma unroll
        for (int i = 0; i < 2; ++i) {
            const int t = q + 4 * wv + 16 * i;
            if (t < 25) {
                const int row = t * 16 + cl;
                u32x4 ar = *reinterpret_cast<const u32x4*>(&Ad[(size_t)row * KP + kk]);
                bf16x8 af = __builtin_bit_cast(bf16x8, ar);
#pragma unroll
                for (int n = 0; n < 4; ++n)
                    acc[i][n] = __builtin_amdgcn_mfma_f32_16x16x32_bf16(
                        af, bf[n], acc[i][n], 0, 0, 0);
            }
        }
    }

    float bv[4];
#pragma unroll
    for (int n = 0; n < 4; ++n) bv[n] = bias[n * 16 + cl];

    float pmax[4];
#pragma unroll
    for (int n = 0; n < 4; ++n) pmax[n] = -3.4e38f;

#pragma unroll
    for (int i = 0; i < 2; ++i) {
        const int t = q + 4 * wv + 16 * i;
        if (t < 25) {
            float y[4][4];
#pragma unroll
            for (int n = 0; n < 4; ++n)
#pragma unroll
                for (int r = 0; r < 4; ++r) y[n][r] = acc[i][n][r] + bv[n];

            float pss[4];
#pragma unroll
            for (int r = 0; r < 4; ++r)
                pss[r] = y[0][r]*y[0][r] + y[1][r]*y[1][r] +
                         y[2][r]*y[2][r] + y[3][r]*y[3][r];
#pragma unroll
            for (int m = 1; m < 16; m <<= 1)
#pragma unroll
                for (int r = 0; r < 4; ++r) pss[r] += __shfl_xor(pss[r], m);

            float rin[4];
#pragma unroll
            for (int r = 0; r < 4; ++r)
                rin[r] = 1.f / fmaxf(sqrtf(pss[r]), 1e-12f);

#pragma unroll
            for (int n = 0; n < 4; ++n)
#pragma unroll
                for (int r = 0; r < 4; ++r) {
                    float z = y[n][r] * rin[r];
                    if (STATS) z = fmaxf(z, 0.f);
                    y[n][r] = z;
                    const int row = t * 16 + g * 4 + r;
                    Zout[((size_t)b * Nn + row) * Hh + n * 16 + cl] = z;
                    if (!STATS) pmax[n] = fmaxf(pmax[n], z);
                }

            if (STATS) {
                float s1[4], s2[4];
#pragma unroll
                for (int r = 0; r < 4; ++r) {
                    s1[r] = y[0][r] + y[1][r] + y[2][r] + y[3][r];
                    s2[r] = y[0][r]*y[0][r] + y[1][r]*y[1][r] +
                            y[2][r]*y[2][r] + y[3][r]*y[3][r];
                }
#pragma unroll
                for (int m = 1; m < 16; m <<= 1)
#pragma unroll
                    for (int r = 0; r < 4; ++r) {
                        s1[r] += __shfl_xor(s1[r], m);
                        s2[r] += __shfl_xor(s2[r], m);
                    }
                if (cl == 0) {
#pragma unroll
                    for (int r = 0; r < 4; ++r) {
                        const int row = t * 16 + g * 4 + r;
                        atomicAdd(&ssum[row], s1[r]);
                        atomicAdd(&ssq[row],  s2[r]);
                    }
                }
            }
        }
    }

    if constexpr (!STATS) {
        // block-local column max -> pmaxq[blockIdx][h]
        __shared__ float sm[4][64];
#pragma unroll
        for (int m = 16; m < 64; m <<= 1)
#pragma unroll
            for (int n = 0; n < 4; ++n)
                pmax[n] = fmaxf(pmax[n], __shfl_xor(pmax[n], m));
        if (lane < 16) {
#pragma unroll
            for (int n = 0; n < 4; ++n) sm[wv][n * 16 + cl] = pmax[n];
        }
        __syncthreads();
        if (tid < 64) {
            float m = fmaxf(fmaxf(sm[0][tid], sm[1][tid]),
                            fmaxf(sm[2][tid], sm[3][tid]));
            pmaxq[(size_t)blockIdx.x * 64 + tid] = m;
        }
    }
}

__global__ void red4max(const float* __restrict__ pmaxq, float* __restrict__ out3) {
    const int b = blockIdx.x, h = threadIdx.x;
    float m = pmaxq[(size_t)(b * 4 + 0) * 64 + h];
    m = fmaxf(m, pmaxq[(size_t)(b * 4 + 1) * 64 + h]);
    m = fmaxf(m, pmaxq[(size_t)(b * 4 + 2) * 64 + h]);
    m = fmaxf(m, pmaxq[(size_t)(b * 4 + 3) * 64 + h]);
    out3[b * 64 + h] = m;
}

__global__ void finalize_stats(const float* __restrict__ ssum,
                               const float* __restrict__ ssq,
                               float* __restrict__ mean, float* __restrict__ inv) {
    int r = threadIdx.x;
    if (r < Nn) {
        float m = ssum[r] * (1.0f / BH_COUNT);
        float v = ssq[r] * (1.0f / BH_COUNT) - m * m;
        mean[r] = m;
        inv[r]  = rsqrtf(v + 1e-5f);
    }
}

// ---------------------------------------------------------------------------
// FC head: h=[out1|out2|out3] (256x192) -> fc1+relu+bn2 -> fc2+relu+bn2 -> fc3
// ---------------------------------------------------------------------------
__global__ __launch_bounds__(1024) void headk(
        const float* __restrict__ out1, const float* __restrict__ out2,
        const float* __restrict__ out3,
        const float* __restrict__ W1f, const float* __restrict__ b1f,
        const float* __restrict__ W2f, const float* __restrict__ b2f,
        const float* __restrict__ W3f, const float* __restrict__ b3f,
        float* __restrict__ ypred) {
    __shared__ float gA[256][64];     // 64 KB activations
    __shared__ float w1s[192 * 64];   // 48 KB
    __shared__ float w2s[64 * 64];    // 16 KB
    __shared__ float mS[64], iS[64];
    const int t = threadIdx.x;
    const int r = t >> 2, q = t & 3;

    for (int i = t; i < 192 * 64; i += 1024) w1s[i] = W1f[i];
    for (int i = t; i < 64 * 64; i += 1024) w2s[i] = W2f[i];
    __syncthreads();

    float acc[16];
#pragma unroll
    for (int j = 0; j < 16; ++j) acc[j] = b1f[q * 16 + j];
    for (int k = 0; k < 192; ++k) {
        float hv = (k < 64) ? out1[r * 64 + k]
                 : (k < 128) ? out2[r * 64 + (k - 64)]
                             : out3[r * 64 + (k - 128)];
#pragma unroll
        for (int j = 0; j < 16; ++j) acc[j] += hv * w1s[k * 64 + q * 16 + j];
    }
#pragma unroll
    for (int j = 0; j < 16; ++j) gA[r][q * 16 + j] = fmaxf(acc[j], 0.f);
    __syncthreads();

    if (t < 64) {
        float s = 0.f, s2 = 0.f;
        for (int rr = 0; rr < 256; ++rr) { float v = gA[rr][t]; s += v; s2 += v * v; }
        float m = s * (1.f / 256.f);
        float var = s2 * (1.f / 256.f) - m * m;
        mS[t] = m;
        iS[t] = rsqrtf(var + 1e-5f);
    }
    __syncthreads();

#pragma unroll
    for (int j = 0; j < 16; ++j) acc[j] = b2f[q * 16 + j];
#pragma unroll
    for (int k = 0; k < 64; ++k) {
        float gn = (gA[r][k] - mS[k]) * iS[k];
#pragma unroll
        for (int j = 0; j < 16; ++j) acc[j] += gn * w2s[k * 64 + q * 16 + j];
    }
    __syncthreads();
#pragma unroll
    for (int j = 0; j < 16; ++j) gA[r][q * 16 + j] = fmaxf(acc[j], 0.f);
    __syncthreads();

    if (t < 64) {
        float s = 0.f, s2 = 0.f;
        for (int rr = 0; rr < 256; ++rr) { float v = gA[rr][t]; s += v; s2 += v * v; }
        float m = s * (1.f / 256.f);
        float var = s2 * (1.f / 256.f) - m * m;
        mS[t] = m;
        iS[t] = rsqrtf(var + 1e-5f);
    }
    __syncthreads();

    if (q < 2) {
        float a = b3f[q];
#pragma unroll
        for (int k = 0; k < 64; ++k) {
            float gn = (gA[r][k] - mS[k]) * iS[k];
            a += gn * W3f[k * 2 + q];
        }
        ypred[r * 2 + q] = a;
    }
}

// ---------------------------------------------------------------------------
extern "C" void kernel_launch(void* const* d_in, const int* in_sizes, int n_in,
                              void* d_out, int out_size, void* d_ws, size_t ws_size,
                              hipStream_t stream) {
    const float* x    = (const float*)d_in[0];
    const int*   arow = (const int*)d_in[1];
    const int*   acol = (const int*)d_in[2];
    const float* aval = (const float*)d_in[3];
    const float* W1 = (const float*)d_in[4];
    const float* b1 = (const float*)d_in[5];
    const float* W2 = (const float*)d_in[6];
    const float* b2 = (const float*)d_in[7];
    const float* W3 = (const float*)d_in[8];
    const float* b3 = (const float*)d_in[9];
    const float* fc1W = (const float*)d_in[10];
    const float* fc1b = (const float*)d_in[11];
    const float* fc2W = (const float*)d_in[12];
    const float* fc2b = (const float*)d_in[13];
    const float* fc3W = (const float*)d_in[14];
    const float* fc3b = (const float*)d_in[15];

    char* w = (char*)d_ws;
    size_t off = 0;
    float* Adf = (float*)(w + off);            off += (size_t)Nn * KP * 4;
    unsigned short* Adbf = (unsigned short*)(w + off); off += (size_t)Nn * KP * 2;
    unsigned short* T1h = (unsigned short*)(w + off); off += (size_t)64 * 416 * 2;
    unsigned short* T1l = (unsigned short*)(w + off); off += (size_t)64 * 416 * 2;
    unsigned short* T2h = (unsigned short*)(w + off); off += (size_t)64 * 64 * 2;
    unsigned short* T2l = (unsigned short*)(w + off); off += (size_t)64 * 64 * 2;
    unsigned short* T3h = (unsigned short*)(w + off); off += (size_t)64 * 64 * 2;
    unsigned short* T3l = (unsigned short*)(w + off); off += (size_t)64 * 64 * 2;
    unsigned short* Ut = (unsigned short*)(w + off); off += (size_t)Bb * 64 * UTP * 2;
    float* Z = (float*)(w + off);              off += (size_t)Mrows * Hh * 4;
    float* stats = (float*)(w + off);          off += 1600 * 4;
    float* ssum1 = stats, *ssq1 = stats + 400, *ssum2 = stats + 800, *ssq2 = stats + 1200;
    float* mean1 = (float*)(w + off); off += 1600;
    float* inv1  = (float*)(w + off); off += 1600;
    float* mean2 = (float*)(w + off); off += 1600;
    float* inv2  = (float*)(w + off); off += 1600;
    float* out1  = (float*)(w + off); off += Bb * Hh * 4;
    float* out2  = (float*)(w + off); off += Bb * Hh * 4;
    float* out3  = (float*)(w + off); off += Bb * Hh * 4;
    float* pmaxq = (float*)(w + off); off += (size_t)Bb * 4 * 64 * 4;

    float* ypred = (float*)d_out;
    float* x3    = (float*)d_out + 512;

    // Prep: densify adjacency (bf16 [400][416]) + split weights
    initk<<<384, 1024, 0, stream>>>(Adf, stats, Ut);
    scatAk<<<(NNZ + 255) / 256, 256, 0, stream>>>(arow, acol, aval, Adf);
    cvtAk<<<(Nn * KP + 1023) / 1024, 1024, 0, stream>>>(Adf, Adbf);
    wprep<<<192, 256, 0, stream>>>(W1, W2, W3, T1h, T1l, T2h, T2l, T3h, T3l);

    // Layer 1
    xg400<<<Mrows / 128, 256, 0, stream>>>(x, T1h, T1l, Ut);
    aggmm<true><<<Bb * 4, 256, 0, stream>>>(Adbf, Ut, b1, Z, ssum1, ssq1, nullptr);
    finalize_stats<<<1, 512, 0, stream>>>(ssum1, ssq1, mean1, inv1);

    // Layer 2 (BN1 elementwise in xgb; out1 max fused, block-local)
    xgb<<<Bb, 512, 0, stream>>>(Z, T2h, T2l, mean1, inv1, Ut, out1);
    aggmm<true><<<Bb * 4, 256, 0, stream>>>(Adbf, Ut, b2, Z, ssum2, ssq2, nullptr);
    finalize_stats<<<1, 512, 0, stream>>>(ssum2, ssq2, mean2, inv2);

    // Layer 3 (BN2 elementwise in xgb; out2 max fused)
    xgb<<<Bb, 512, 0, stream>>>(Z, T3h, T3l, mean2, inv2, Ut, out2);
    aggmm<false><<<Bb * 4, 256, 0, stream>>>(Adbf, Ut, b3, x3, nullptr, nullptr, pmaxq);
    red4max<<<Bb, 64, 0, stream>>>(pmaxq, out3);

    // FC head
    headk<<<1, 1024, 0, stream>>>(out1, out2, out3, fc1W, fc1b, fc2W, fc2b,
                                  fc3W, fc3b, ypred);
}

// Round 10
// 305.111 us; speedup vs baseline: 1.2945x; 1.0434x over previous
//
#include <hip/hip_runtime.h>
#include <hip/hip_bf16.h>
#include <math.h>

// Problem constants
#define Bb   256
#define Nn   400
#define FIN  400
#define Hh   64
#define NNZ  16000
#define Mrows (Bb*Nn)          // 102400
#define KP   416               // dense-adj K padded to 13*32 for MFMA
#define UTP  416               // Ut node-dim stride (shorts), layer-1 only
#define UPAD 420               // fused-kernel LDS node stride (shorts)
#define BH_COUNT 16384.0f      // B*H for BN3 stats

typedef unsigned int  u32x2 __attribute__((ext_vector_type(2)));
typedef unsigned int  u32x4 __attribute__((ext_vector_type(4)));
typedef __bf16        bf16x8 __attribute__((ext_vector_type(8)));
typedef float         f32x4 __attribute__((ext_vector_type(4)));

__device__ __forceinline__ unsigned int f2bf(float x) {
    unsigned int u = __builtin_bit_cast(unsigned int, x);
    return (u + 0x7FFFu + ((u >> 16) & 1u)) >> 16;   // RNE
}
__device__ __forceinline__ float bf2f(unsigned int h) {
    unsigned int u = h << 16;
    return __builtin_bit_cast(float, u);
}

// ---------------------------------------------------------------------------
// init: zero dense-A f32 accumulator, BN stats, Ut node-pad (400..415)
// ---------------------------------------------------------------------------
__global__ void initk(float* __restrict__ Adf, float* __restrict__ stats,
                      unsigned short* __restrict__ Ut) {
    int t = blockIdx.x * blockDim.x + threadIdx.x;
    if (t < Nn * KP) Adf[t] = 0.f;
    if (t < 1600) stats[t] = 0.f;   // ssum1, ssq1, ssum2, ssq2 (4 x 400)
    if (t < Bb * Hh * 16) {
        int bh = t >> 4, k = Nn + (t & 15);
        Ut[(size_t)bh * UTP + k] = 0;
    }
}

__global__ void scatAk(const int* __restrict__ rows, const int* __restrict__ cols,
                       const float* __restrict__ vals, float* __restrict__ Adf) {
    int i = blockIdx.x * blockDim.x + threadIdx.x;
    if (i < NNZ) atomicAdd(&Adf[rows[i] * KP + cols[i]], vals[i]);
}

__global__ void cvtAk(const float* __restrict__ Adf, unsigned short* __restrict__ Adbf) {
    int i = blockIdx.x * blockDim.x + threadIdx.x;
    if (i < Nn * KP) Adbf[i] = (unsigned short)f2bf(Adf[i]);
}

// ---------------------------------------------------------------------------
// W prep: split W[KT][64] -> hi/lo bf16 in B-fragment layout [col][KPAD]
// ---------------------------------------------------------------------------
__global__ __launch_bounds__(256) void wprep(
        const float* __restrict__ W1, const float* __restrict__ W2,
        const float* __restrict__ W3,
        unsigned short* __restrict__ T1h, unsigned short* __restrict__ T1l,
        unsigned short* __restrict__ T2h, unsigned short* __restrict__ T2l,
        unsigned short* __restrict__ T3h, unsigned short* __restrict__ T3l) {
    const int w = blockIdx.x >> 6;        // 0,1,2
    const int c = blockIdx.x & 63;
    const float* W = (w == 0) ? W1 : (w == 1) ? W2 : W3;
    const int KT   = (w == 0) ? FIN : Hh;
    const int KPAD = (w == 0) ? 416 : 64;
    unsigned short* Th = (w == 0) ? T1h : (w == 1) ? T2h : T3h;
    unsigned short* Tl = (w == 0) ? T1l : (w == 1) ? T2l : T3l;

    for (int k = threadIdx.x; k < KPAD; k += 256) {
        float v = (k < KT) ? W[k * 64 + c] : 0.f;
        unsigned int hb = f2bf(v);
        Th[c * KPAD + k] = (unsigned short)hb;
        Tl[c * KPAD + k] = (unsigned short)f2bf(v - bf2f(hb));
    }
}

// ---------------------------------------------------------------------------
// Layer-1 GEMM (split precision, LDS-free, pipelined) — R8-proven:
//   Ut = x[M,400](f32) @ W1[400,64]  -> bf16, transposed per batch
// ---------------------------------------------------------------------------
__global__ __launch_bounds__(256) void xg400(
        const float* __restrict__ A,
        const unsigned short* __restrict__ Wth,
        const unsigned short* __restrict__ Wtl,
        unsigned short* __restrict__ Ut) {
    const int tid  = threadIdx.x;
    const int wv   = tid >> 6;
    const int lane = tid & 63;
    const int cl   = lane & 15;
    const int g    = lane >> 4;
    const int m0   = blockIdx.x * 128;
    const int rowA = m0 + wv * 32 + cl;
    const int rowB = rowA + 16;

    f32x4 acc[2][4];
#pragma unroll
    for (int t2 = 0; t2 < 2; ++t2)
#pragma unroll
        for (int n = 0; n < 4; ++n) acc[t2][n] = f32x4{0.f, 0.f, 0.f, 0.f};

    auto loadA = [&](int s, float4& l0, float4& h0, float4& l1, float4& h1) {
        int kk = s * 32 + g * 8;
        int kc = kk > 392 ? 392 : kk;                 // clamp (W pad is zero)
        const float* p = &A[(size_t)rowA * FIN + kc];
        l0 = *reinterpret_cast<const float4*>(p);
        h0 = *reinterpret_cast<const float4*>(p + 4);
        const float* q = &A[(size_t)rowB * FIN + kc];
        l1 = *reinterpret_cast<const float4*>(q);
        h1 = *reinterpret_cast<const float4*>(q + 4);
    };
    auto loadW = [&](int s, u32x4* dst) {
        int kk = s * 32 + g * 8;
#pragma unroll
        for (int n = 0; n < 4; ++n) {
            dst[n]     = *reinterpret_cast<const u32x4*>(&Wth[(size_t)(n * 16 + cl) * 416 + kk]);
            dst[4 + n] = *reinterpret_cast<const u32x4*>(&Wtl[(size_t)(n * 16 + cl) * 416 + kk]);
        }
    };
    auto split = [&](const float4& lo, const float4& hi, bf16x8& ah, bf16x8& al) {
        float v0 = lo.x, v1 = lo.y, v2 = lo.z, v3 = lo.w;
        float v4 = hi.x, v5 = hi.y, v6 = hi.z, v7 = hi.w;
        unsigned h0, h1;
        u32x4 hw, lw;
        h0 = f2bf(v0); h1 = f2bf(v1);
        hw[0] = h0 | (h1 << 16);
        lw[0] = f2bf(v0 - bf2f(h0)) | (f2bf(v1 - bf2f(h1)) << 16);
        h0 = f2bf(v2); h1 = f2bf(v3);
        hw[1] = h0 | (h1 << 16);
        lw[1] = f2bf(v2 - bf2f(h0)) | (f2bf(v3 - bf2f(h1)) << 16);
        h0 = f2bf(v4); h1 = f2bf(v5);
        hw[2] = h0 | (h1 << 16);
        lw[2] = f2bf(v4 - bf2f(h0)) | (f2bf(v5 - bf2f(h1)) << 16);
        h0 = f2bf(v6); h1 = f2bf(v7);
        hw[3] = h0 | (h1 << 16);
        lw[3] = f2bf(v6 - bf2f(h0)) | (f2bf(v7 - bf2f(h1)) << 16);
        ah = __builtin_bit_cast(bf16x8, hw);
        al = __builtin_bit_cast(bf16x8, lw);
    };

    float4 cAl0, cAh0, cAl1, cAh1, nAl0, nAh0, nAl1, nAh1;
    u32x4  cW[8], nW[8];
    loadA(0, cAl0, cAh0, cAl1, cAh1);
    loadW(0, cW);

    for (int s = 0; s < 13; ++s) {
        if (s < 12) {
            loadA(s + 1, nAl0, nAh0, nAl1, nAh1);
            loadW(s + 1, nW);
        }
        bf16x8 ah0, al0, ah1, al1;
        split(cAl0, cAh0, ah0, al0);
        split(cAl1, cAh1, ah1, al1);
#pragma unroll
        for (int n = 0; n < 4; ++n) {
            bf16x8 bh = __builtin_bit_cast(bf16x8, cW[n]);
            bf16x8 bl = __builtin_bit_cast(bf16x8, cW[4 + n]);
            acc[0][n] = __builtin_amdgcn_mfma_f32_16x16x32_bf16(ah0, bh, acc[0][n], 0, 0, 0);
            acc[0][n] = __builtin_amdgcn_mfma_f32_16x16x32_bf16(ah0, bl, acc[0][n], 0, 0, 0);
            acc[0][n] = __builtin_amdgcn_mfma_f32_16x16x32_bf16(al0, bh, acc[0][n], 0, 0, 0);
            acc[1][n] = __builtin_amdgcn_mfma_f32_16x16x32_bf16(ah1, bh, acc[1][n], 0, 0, 0);
            acc[1][n] = __builtin_amdgcn_mfma_f32_16x16x32_bf16(ah1, bl, acc[1][n], 0, 0, 0);
            acc[1][n] = __builtin_amdgcn_mfma_f32_16x16x32_bf16(al1, bh, acc[1][n], 0, 0, 0);
        }
        if (s < 12) {
            cAl0 = nAl0; cAh0 = nAh0; cAl1 = nAl1; cAh1 = nAh1;
#pragma unroll
            for (int j = 0; j < 8; ++j) cW[j] = nW[j];
        }
    }

#pragma unroll
    for (int t2 = 0; t2 < 2; ++t2) {
        const int row0  = m0 + wv * 32 + t2 * 16 + g * 4;
        const int b     = row0 / Nn;
        const int node0 = row0 - b * Nn;
#pragma unroll
        for (int n = 0; n < 4; ++n) {
            const int col = n * 16 + cl;
            u32x2 pk;
            pk[0] = f2bf(acc[t2][n][0]) | (f2bf(acc[t2][n][1]) << 16);
            pk[1] = f2bf(acc[t2][n][2]) | (f2bf(acc[t2][n][3]) << 16);
            *reinterpret_cast<u32x2*>(&Ut[((size_t)b * 64 + col) * UTP + node0]) = pk;
        }
    }
}

// ---------------------------------------------------------------------------
// Layer-1 aggregation (R9-proven): Z[b] = relu(normalize(Adj@U[b] + b1)),
// + BN stats. 4 blocks per batch, reads Ut from global.
// ---------------------------------------------------------------------------
__global__ __launch_bounds__(256) void aggmm(
        const unsigned short* __restrict__ Ad,
        const unsigned short* __restrict__ Ut,
        const float* __restrict__ bias,
        float* __restrict__ Zout,
        float* __restrict__ ssum, float* __restrict__ ssq) {
    const int b    = blockIdx.x >> 2;
    const int q    = blockIdx.x & 3;
    const int tid  = threadIdx.x;
    const int lane = tid & 63;
    const int wv   = tid >> 6;
    const int cl   = lane & 15;
    const int g    = lane >> 4;
    const unsigned short* __restrict__ Ub = Ut + (size_t)b * 64 * UTP;

    f32x4 acc[2][4];
#pragma unroll
    for (int i = 0; i < 2; ++i)
#pragma unroll
        for (int n = 0; n < 4; ++n) acc[i][n] = f32x4{0.f, 0.f, 0.f, 0.f};

    for (int k0 = 0; k0 < KP; k0 += 32) {
        const int kk = k0 + g * 8;
        bf16x8 bf[4];
#pragma unroll
        for (int n = 0; n < 4; ++n) {
            u32x4 w = *reinterpret_cast<const u32x4*>(&Ub[(size_t)(n * 16 + cl) * UTP + kk]);
            bf[n] = __builtin_bit_cast(bf16x8, w);
        }
#pragma unroll
        for (int i = 0; i < 2; ++i) {
            const int t = q + 4 * wv + 16 * i;
            if (t < 25) {
                const int row = t * 16 + cl;
                u32x4 ar = *reinterpret_cast<const u32x4*>(&Ad[(size_t)row * KP + kk]);
                bf16x8 af = __builtin_bit_cast(bf16x8, ar);
#pragma unroll
                for (int n = 0; n < 4; ++n)
                    acc[i][n] = __builtin_amdgcn_mfma_f32_16x16x32_bf16(
                        af, bf[n], acc[i][n], 0, 0, 0);
            }
        }
    }

    float bv[4];
#pragma unroll
    for (int n = 0; n < 4; ++n) bv[n] = bias[n * 16 + cl];

#pragma unroll
    for (int i = 0; i < 2; ++i) {
        const int t = q + 4 * wv + 16 * i;
        if (t < 25) {
            float y[4][4];
#pragma unroll
            for (int n = 0; n < 4; ++n)
#pragma unroll
                for (int r = 0; r < 4; ++r) y[n][r] = acc[i][n][r] + bv[n];

            float pss[4];
#pragma unroll
            for (int r = 0; r < 4; ++r)
                pss[r] = y[0][r]*y[0][r] + y[1][r]*y[1][r] +
                         y[2][r]*y[2][r] + y[3][r]*y[3][r];
#pragma unroll
            for (int m = 1; m < 16; m <<= 1)
#pragma unroll
                for (int r = 0; r < 4; ++r) pss[r] += __shfl_xor(pss[r], m);

            float rin[4];
#pragma unroll
            for (int r = 0; r < 4; ++r)
                rin[r] = 1.f / fmaxf(sqrtf(pss[r]), 1e-12f);

            float s1[4], s2[4];
#pragma unroll
            for (int r = 0; r < 4; ++r) { s1[r] = 0.f; s2[r] = 0.f; }
#pragma unroll
            for (int n = 0; n < 4; ++n)
#pragma unroll
                for (int r = 0; r < 4; ++r) {
                    float z = fmaxf(y[n][r] * rin[r], 0.f);
                    const int row = t * 16 + g * 4 + r;
                    Zout[((size_t)b * Nn + row) * Hh + n * 16 + cl] = z;
                    s1[r] += z;
                    s2[r] += z * z;
                }
#pragma unroll
            for (int m = 1; m < 16; m <<= 1)
#pragma unroll
                for (int r = 0; r < 4; ++r) {
                    s1[r] += __shfl_xor(s1[r], m);
                    s2[r] += __shfl_xor(s2[r], m);
                }
            if (cl == 0) {
#pragma unroll
                for (int r = 0; r < 4; ++r) {
                    const int row = t * 16 + g * 4 + r;
                    atomicAdd(&ssum[row], s1[r]);
                    atomicAdd(&ssq[row],  s2[r]);
                }
            }
        }
    }
}

__global__ void finalize_stats(const float* __restrict__ ssum,
                               const float* __restrict__ ssq,
                               float* __restrict__ mean, float* __restrict__ inv) {
    int r = threadIdx.x;
    if (r < Nn) {
        float m = ssum[r] * (1.0f / BH_COUNT);
        float v = ssq[r] * (1.0f / BH_COUNT) - m * m;
        mean[r] = m;
        inv[r]  = rsqrtf(v + 1e-5f);
    }
}

// ---------------------------------------------------------------------------
// Fused layer 2/3: block = ONE BATCH (grid 256, 8 waves, 512 thr).
// Phase A (per tile t=wv+8i, i<4, t<25):
//   za = (Zin[b,node]-mean[node])*inv[node];  track max(za) -> outmax_za
//   U = za @ W (split-precision MFMA) -> LDS Us[col][node] bf16 (UPAD=420)
// sync
// Phase B (2 sweeps x 2 tiles, t=wv+8*(i2+2*s2), t<25):
//   Y = Adj @ U + bias;  z = normalize(Y)
//   STATS: z=relu(z) -> Zout + BN stat atomics
//   else : z -> x3 (d_out) + block-local column max -> out3
// Numerics identical to R9's xgb+aggmm pair (same f2bf points, MFMA order).
// ---------------------------------------------------------------------------
template <bool STATS>
__global__ __launch_bounds__(512) void fusedl(
        const float* __restrict__ Zin,
        const unsigned short* __restrict__ Ad,
        const unsigned short* __restrict__ Wth,   // [64][64] frag layout
        const unsigned short* __restrict__ Wtl,
        const float* __restrict__ mean, const float* __restrict__ inv,
        const float* __restrict__ bias,
        float* __restrict__ Zout,                 // Z (STATS) or x3 (d_out)
        float* __restrict__ ssum, float* __restrict__ ssq,
        float* __restrict__ outmax_za,            // out1 / out2 [B][64]
        float* __restrict__ out3) {               // [B][64] (!STATS)
    __shared__ unsigned short Us[64 * UPAD];      // 53760 B
    __shared__ float sred[8][64];
    const int b    = blockIdx.x;
    const int tid  = threadIdx.x;
    const int wv   = tid >> 6;
    const int lane = tid & 63;
    const int cl   = lane & 15;
    const int g    = lane >> 4;

    // zero LDS pad rows (node 400..419)
    for (int i = tid; i < 64 * (UPAD - Nn); i += 512) {
        int c = i / (UPAD - Nn), k = Nn + i % (UPAD - Nn);
        Us[c * UPAD + k] = 0;
    }

    float vmax[16];
#pragma unroll
    for (int j = 0; j < 16; ++j) vmax[j] = -3.4e38f;

    // ---- Phase A: affine + max + za@W -> LDS ----
    for (int i = 0; i < 4; ++i) {
        const int t = wv + 8 * i;
        if (t < 25) {
            const int node = t * 16 + cl;
            const float mm = mean[node], iv = inv[node];

            float za[16];
#pragma unroll
            for (int s = 0; s < 2; ++s) {
                const float* p = &Zin[((size_t)b * Nn + node) * 64 + s * 32 + g * 8];
                float4 lo = *reinterpret_cast<const float4*>(p);
                float4 hi = *reinterpret_cast<const float4*>(p + 4);
                za[s * 8 + 0] = (lo.x - mm) * iv;
                za[s * 8 + 1] = (lo.y - mm) * iv;
                za[s * 8 + 2] = (lo.z - mm) * iv;
                za[s * 8 + 3] = (lo.w - mm) * iv;
                za[s * 8 + 4] = (hi.x - mm) * iv;
                za[s * 8 + 5] = (hi.y - mm) * iv;
                za[s * 8 + 6] = (hi.z - mm) * iv;
                za[s * 8 + 7] = (hi.w - mm) * iv;
            }
#pragma unroll
            for (int j = 0; j < 16; ++j) vmax[j] = fmaxf(vmax[j], za[j]);

            f32x4 acc[4];
#pragma unroll
            for (int n = 0; n < 4; ++n) acc[n] = f32x4{0.f, 0.f, 0.f, 0.f};

#pragma unroll
            for (int s = 0; s < 2; ++s) {
                u32x4 hw, lw;
#pragma unroll
                for (int j = 0; j < 4; ++j) {
                    unsigned h0 = f2bf(za[s * 8 + 2 * j]);
                    unsigned h1 = f2bf(za[s * 8 + 2 * j + 1]);
                    hw[j] = h0 | (h1 << 16);
                    lw[j] = f2bf(za[s * 8 + 2 * j] - bf2f(h0)) |
                            (f2bf(za[s * 8 + 2 * j + 1] - bf2f(h1)) << 16);
                }
                bf16x8 ah = __builtin_bit_cast(bf16x8, hw);
                bf16x8 al = __builtin_bit_cast(bf16x8, lw);
                const int kk = s * 32 + g * 8;
#pragma unroll
                for (int n = 0; n < 4; ++n) {
                    u32x4 bhw = *reinterpret_cast<const u32x4*>(&Wth[(size_t)(n * 16 + cl) * 64 + kk]);
                    u32x4 blw = *reinterpret_cast<const u32x4*>(&Wtl[(size_t)(n * 16 + cl) * 64 + kk]);
                    bf16x8 bh = __builtin_bit_cast(bf16x8, bhw);
                    bf16x8 bl = __builtin_bit_cast(bf16x8, blw);
                    acc[n] = __builtin_amdgcn_mfma_f32_16x16x32_bf16(ah, bh, acc[n], 0, 0, 0);
                    acc[n] = __builtin_amdgcn_mfma_f32_16x16x32_bf16(ah, bl, acc[n], 0, 0, 0);
                    acc[n] = __builtin_amdgcn_mfma_f32_16x16x32_bf16(al, bh, acc[n], 0, 0, 0);
                }
            }

            const int node0 = t * 16 + g * 4;
#pragma unroll
            for (int n = 0; n < 4; ++n) {
                const int col = n * 16 + cl;
                u32x2 pk;
                pk[0] = f2bf(acc[n][0]) | (f2bf(acc[n][1]) << 16);
                pk[1] = f2bf(acc[n][2]) | (f2bf(acc[n][3]) << 16);
                *reinterpret_cast<u32x2*>(&Us[col * UPAD + node0]) = pk;
            }
        }
    }

    // za-max: reduce over cl (nodes within wave), stash per wave
#pragma unroll
    for (int m = 1; m < 16; m <<= 1)
#pragma unroll
        for (int j = 0; j < 16; ++j)
            vmax[j] = fmaxf(vmax[j], __shfl_xor(vmax[j], m));
    if (cl == 0) {
#pragma unroll
        for (int j = 0; j < 16; ++j) {
            const int h = 32 * (j >> 3) + g * 8 + (j & 7);
            sred[wv][h] = vmax[j];
        }
    }
    __syncthreads();          // covers Us writes + sred
    if (tid < 64) {
        float m = sred[0][tid];
#pragma unroll
        for (int w = 1; w < 8; ++w) m = fmaxf(m, sred[w][tid]);
        outmax_za[b * 64 + tid] = m;
    }

    // ---- Phase B: Adj @ U (from LDS) ----
    const float bv0 = bias[cl],      bv1 = bias[16 + cl],
                bv2 = bias[32 + cl], bv3 = bias[48 + cl];
    float pmax[4];
#pragma unroll
    for (int n = 0; n < 4; ++n) pmax[n] = -3.4e38f;

#pragma unroll
    for (int s2 = 0; s2 < 2; ++s2) {
        f32x4 acc[2][4];
#pragma unroll
        for (int i = 0; i < 2; ++i)
#pragma unroll
            for (int n = 0; n < 4; ++n) acc[i][n] = f32x4{0.f, 0.f, 0.f, 0.f};

        for (int k0 = 0; k0 < KP; k0 += 32) {
            const int kk = k0 + g * 8;
            bf16x8 bf[4];
#pragma unroll
            for (int n = 0; n < 4; ++n) {
                const unsigned short* p = &Us[(n * 16 + cl) * UPAD + kk];
                u32x2 lo = *reinterpret_cast<const u32x2*>(p);
                u32x2 hi = *reinterpret_cast<const u32x2*>(p + 4);
                u32x4 w; w[0] = lo[0]; w[1] = lo[1]; w[2] = hi[0]; w[3] = hi[1];
                bf[n] = __builtin_bit_cast(bf16x8, w);
            }
#pragma unroll
            for (int i = 0; i < 2; ++i) {
                const int t = wv + 8 * (i + 2 * s2);
                if (t < 25) {
                    const int row = t * 16 + cl;
                    u32x4 ar = *reinterpret_cast<const u32x4*>(&Ad[(size_t)row * KP + kk]);
                    bf16x8 af = __builtin_bit_cast(bf16x8, ar);
#pragma unroll
                    for (int n = 0; n < 4; ++n)
                        acc[i][n] = __builtin_amdgcn_mfma_f32_16x16x32_bf16(
                            af, bf[n], acc[i][n], 0, 0, 0);
                }
            }
        }

#pragma unroll
        for (int i = 0; i < 2; ++i) {
            const int t = wv + 8 * (i + 2 * s2);
            if (t < 25) {
                float y[4][4];
                const float bvs[4] = {bv0, bv1, bv2, bv3};
#pragma unroll
                for (int n = 0; n < 4; ++n)
#pragma unroll
                    for (int r = 0; r < 4; ++r) y[n][r] = acc[i][n][r] + bvs[n];

                float pss[4];
#pragma unroll
                for (int r = 0; r < 4; ++r)
                    pss[r] = y[0][r]*y[0][r] + y[1][r]*y[1][r] +
                             y[2][r]*y[2][r] + y[3][r]*y[3][r];
#pragma unroll
                for (int m = 1; m < 16; m <<= 1)
#pragma unroll
                    for (int r = 0; r < 4; ++r) pss[r] += __shfl_xor(pss[r], m);

                float rin[4];
#pragma unroll
                for (int r = 0; r < 4; ++r)
                    rin[r] = 1.f / fmaxf(sqrtf(pss[r]), 1e-12f);

                float s1[4], s2a[4];
#pragma unroll
                for (int r = 0; r < 4; ++r) { s1[r] = 0.f; s2a[r] = 0.f; }
#pragma unroll
                for (int n = 0; n < 4; ++n)
#pragma unroll
                    for (int r = 0; r < 4; ++r) {
                        float z = y[n][r] * rin[r];
                        if (STATS) z = fmaxf(z, 0.f);
                        const int row = t * 16 + g * 4 + r;
                        Zout[((size_t)b * Nn + row) * Hh + n * 16 + cl] = z;
                        if (STATS) { s1[r] += z; s2a[r] += z * z; }
                        else        pmax[n] = fmaxf(pmax[n], z);
                    }

                if (STATS) {
#pragma unroll
                    for (int m = 1; m < 16; m <<= 1)
#pragma unroll
                        for (int r = 0; r < 4; ++r) {
                            s1[r]  += __shfl_xor(s1[r], m);
                            s2a[r] += __shfl_xor(s2a[r], m);
                        }
                    if (cl == 0) {
#pragma unroll
                        for (int r = 0; r < 4; ++r) {
                            const int row = t * 16 + g * 4 + r;
                            atomicAdd(&ssum[row], s1[r]);
                            atomicAdd(&ssq[row],  s2a[r]);
                        }
                    }
                }
            }
        }
    }

    if constexpr (!STATS) {
        // block-local column max over all 400 rows -> out3[b][h]
        __syncthreads();
#pragma unroll
        for (int m = 16; m < 64; m <<= 1)
#pragma unroll
            for (int n = 0; n < 4; ++n)
                pmax[n] = fmaxf(pmax[n], __shfl_xor(pmax[n], m));
        if (lane < 16) {
#pragma unroll
            for (int n = 0; n < 4; ++n) sred[wv][n * 16 + cl] = pmax[n];
        }
        __syncthreads();
        if (tid < 64) {
            float m = sred[0][tid];
#pragma unroll
            for (int w = 1; w < 8; ++w) m = fmaxf(m, sred[w][tid]);
            out3[b * 64 + tid] = m;
        }
    }
}

// ---------------------------------------------------------------------------
// FC head: h=[out1|out2|out3] (256x192) -> fc1+relu+bn2 -> fc2+relu+bn2 -> fc3
// ---------------------------------------------------------------------------
__global__ __launch_bounds__(1024) void headk(
        const float* __restrict__ out1, const float* __restrict__ out2,
        const float* __restrict__ out3,
        const float* __restrict__ W1f, const float* __restrict__ b1f,
        const float* __restrict__ W2f, const float* __restrict__ b2f,
        const float* __restrict__ W3f, const float* __restrict__ b3f,
        float* __restrict__ ypred) {
    __shared__ float gA[256][64];     // 64 KB activations
    __shared__ float w1s[192 * 64];   // 48 KB
    __shared__ float w2s[64 * 64];    // 16 KB
    __shared__ float mS[64], iS[64];
    const int t = threadIdx.x;
    const int r = t >> 2, q = t & 3;

    for (int i = t; i < 192 * 64; i += 1024) w1s[i] = W1f[i];
    for (int i = t; i < 64 * 64; i += 1024) w2s[i] = W2f[i];
    __syncthreads();

    float acc[16];
#pragma unroll
    for (int j = 0; j < 16; ++j) acc[j] = b1f[q * 16 + j];
    for (int k = 0; k < 192; ++k) {
        float hv = (k < 64) ? out1[r * 64 + k]
                 : (k < 128) ? out2[r * 64 + (k - 64)]
                             : out3[r * 64 + (k - 128)];
#pragma unroll
        for (int j = 0; j < 16; ++j) acc[j] += hv * w1s[k * 64 + q * 16 + j];
    }
#pragma unroll
    for (int j = 0; j < 16; ++j) gA[r][q * 16 + j] = fmaxf(acc[j], 0.f);
    __syncthreads();

    if (t < 64) {
        float s = 0.f, s2 = 0.f;
        for (int rr = 0; rr < 256; ++rr) { float v = gA[rr][t]; s += v; s2 += v * v; }
        float m = s * (1.f / 256.f);
        float var = s2 * (1.f / 256.f) - m * m;
        mS[t] = m;
        iS[t] = rsqrtf(var + 1e-5f);
    }
    __syncthreads();

#pragma unroll
    for (int j = 0; j < 16; ++j) acc[j] = b2f[q * 16 + j];
#pragma unroll
    for (int k = 0; k < 64; ++k) {
        float gn = (gA[r][k] - mS[k]) * iS[k];
#pragma unroll
        for (int j = 0; j < 16; ++j) acc[j] += gn * w2s[k * 64 + q * 16 + j];
    }
    __syncthreads();
#pragma unroll
    for (int j = 0; j < 16; ++j) gA[r][q * 16 + j] = fmaxf(acc[j], 0.f);
    __syncthreads();

    if (t < 64) {
        float s = 0.f, s2 = 0.f;
        for (int rr = 0; rr < 256; ++rr) { float v = gA[rr][t]; s += v; s2 += v * v; }
        float m = s * (1.f / 256.f);
        float var = s2 * (1.f / 256.f) - m * m;
        mS[t] = m;
        iS[t] = rsqrtf(var + 1e-5f);
    }
    __syncthreads();

    if (q < 2) {
        float a = b3f[q];
#pragma unroll
        for (int k = 0; k < 64; ++k) {
            float gn = (gA[r][k] - mS[k]) * iS[k];
            a += gn * W3f[k * 2 + q];
        }
        ypred[r * 2 + q] = a;
    }
}

// ---------------------------------------------------------------------------
extern "C" void kernel_launch(void* const* d_in, const int* in_sizes, int n_in,
                              void* d_out, int out_size, void* d_ws, size_t ws_size,
                              hipStream_t stream) {
    const float* x    = (const float*)d_in[0];
    const int*   arow = (const int*)d_in[1];
    const int*   acol = (const int*)d_in[2];
    const float* aval = (const float*)d_in[3];
    const float* W1 = (const float*)d_in[4];
    const float* b1 = (const float*)d_in[5];
    const float* W2 = (const float*)d_in[6];
    const float* b2 = (const float*)d_in[7];
    const float* W3 = (const float*)d_in[8];
    const float* b3 = (const float*)d_in[9];
    const float* fc1W = (const float*)d_in[10];
    const float* fc1b = (const float*)d_in[11];
    const float* fc2W = (const float*)d_in[12];
    const float* fc2b = (const float*)d_in[13];
    const float* fc3W = (const float*)d_in[14];
    const float* fc3b = (const float*)d_in[15];

    char* w = (char*)d_ws;
    size_t off = 0;
    float* Adf = (float*)(w + off);            off += (size_t)Nn * KP * 4;
    unsigned short* Adbf = (unsigned short*)(w + off); off += (size_t)Nn * KP * 2;
    unsigned short* T1h = (unsigned short*)(w + off); off += (size_t)64 * 416 * 2;
    unsigned short* T1l = (unsigned short*)(w + off); off += (size_t)64 * 416 * 2;
    unsigned short* T2h = (unsigned short*)(w + off); off += (size_t)64 * 64 * 2;
    unsigned short* T2l = (unsigned short*)(w + off); off += (size_t)64 * 64 * 2;
    unsigned short* T3h = (unsigned short*)(w + off); off += (size_t)64 * 64 * 2;
    unsigned short* T3l = (unsigned short*)(w + off); off += (size_t)64 * 64 * 2;
    unsigned short* Ut = (unsigned short*)(w + off); off += (size_t)Bb * 64 * UTP * 2;
    float* Z1 = (float*)(w + off);             off += (size_t)Mrows * Hh * 4;
    float* Z2 = (float*)(w + off);             off += (size_t)Mrows * Hh * 4;
    float* stats = (float*)(w + off);          off += 1600 * 4;
    float* ssum1 = stats, *ssq1 = stats + 400, *ssum2 = stats + 800, *ssq2 = stats + 1200;
    float* mean1 = (float*)(w + off); off += 1600;
    float* inv1  = (float*)(w + off); off += 1600;
    float* mean2 = (float*)(w + off); off += 1600;
    float* inv2  = (float*)(w + off); off += 1600;
    float* out1  = (float*)(w + off); off += Bb * Hh * 4;
    float* out2  = (float*)(w + off); off += Bb * Hh * 4;
    float* out3  = (float*)(w + off); off += Bb * Hh * 4;

    float* ypred = (float*)d_out;
    float* x3    = (float*)d_out + 512;

    // Prep: densify adjacency (bf16 [400][416]) + split weights
    initk<<<384, 1024, 0, stream>>>(Adf, stats, Ut);
    scatAk<<<(NNZ + 255) / 256, 256, 0, stream>>>(arow, acol, aval, Adf);
    cvtAk<<<(Nn * KP + 1023) / 1024, 1024, 0, stream>>>(Adf, Adbf);
    wprep<<<192, 256, 0, stream>>>(W1, W2, W3, T1h, T1l, T2h, T2l, T3h, T3l);

    // Layer 1
    xg400<<<Mrows / 128, 256, 0, stream>>>(x, T1h, T1l, Ut);
    aggmm<<<Bb * 4, 256, 0, stream>>>(Adbf, Ut, b1, Z1, ssum1, ssq1);
    finalize_stats<<<1, 512, 0, stream>>>(ssum1, ssq1, mean1, inv1);

    // Layer 2 fused: BN1 affine + out1-max + za@W2 (LDS) + Adj@U2 + stats2
    fusedl<true><<<Bb, 512, 0, stream>>>(Z1, Adbf, T2h, T2l, mean1, inv1, b2,
                                         Z2, ssum2, ssq2, out1, nullptr);
    finalize_stats<<<1, 512, 0, stream>>>(ssum2, ssq2, mean2, inv2);

    // Layer 3 fused: BN2 affine + out2-max + za@W3 (LDS) + Adj@U3 -> x3 + out3
    fusedl<false><<<Bb, 512, 0, stream>>>(Z2, Adbf, T3h, T3l, mean2, inv2, b3,
                                          x3, nullptr, nullptr, out2, out3);

    // FC head
    headk<<<1, 1024, 0, stream>>>(out1, out2, out3, fc1W, fc1b, fc2W, fc2b,
                                  fc3W, fc3b, ypred);
}

// Round 11
// 301.017 us; speedup vs baseline: 1.3121x; 1.0136x over previous
//
#include <hip/hip_runtime.h>
#include <hip/hip_bf16.h>
#include <math.h>

// Problem constants
#define Bb   256
#define Nn   400
#define FIN  400
#define Hh   64
#define NNZ  16000
#define Mrows (Bb*Nn)          // 102400
#define KP   416               // dense-adj K padded to 13*32 for MFMA
#define UTP  416               // Ut node-dim stride (shorts), layer-1 only
#define UPAD 420               // fused-kernel LDS node stride (shorts)
#define BH_COUNT 16384.0f      // B*H for BN3 stats

typedef unsigned int  u32x2 __attribute__((ext_vector_type(2)));
typedef unsigned int  u32x4 __attribute__((ext_vector_type(4)));
typedef __bf16        bf16x8 __attribute__((ext_vector_type(8)));
typedef float         f32x4 __attribute__((ext_vector_type(4)));

__device__ __forceinline__ unsigned int f2bf(float x) {
    unsigned int u = __builtin_bit_cast(unsigned int, x);
    return (u + 0x7FFFu + ((u >> 16) & 1u)) >> 16;   // RNE
}
__device__ __forceinline__ float bf2f(unsigned int h) {
    unsigned int u = h << 16;
    return __builtin_bit_cast(float, u);
}

// ---------------------------------------------------------------------------
// init: zero dense-A f32 accumulator, BN stats, Ut node-pad (400..415)
// ---------------------------------------------------------------------------
__global__ void initk(float* __restrict__ Adf, float* __restrict__ stats,
                      unsigned short* __restrict__ Ut) {
    int t = blockIdx.x * blockDim.x + threadIdx.x;
    if (t < Nn * KP) Adf[t] = 0.f;
    if (t < 1600) stats[t] = 0.f;   // ssum1, ssq1, ssum2, ssq2 (4 x 400)
    if (t < Bb * Hh * 16) {
        int bh = t >> 4, k = Nn + (t & 15);
        Ut[(size_t)bh * UTP + k] = 0;
    }
}

__global__ void scatAk(const int* __restrict__ rows, const int* __restrict__ cols,
                       const float* __restrict__ vals, float* __restrict__ Adf) {
    int i = blockIdx.x * blockDim.x + threadIdx.x;
    if (i < NNZ) atomicAdd(&Adf[rows[i] * KP + cols[i]], vals[i]);
}

__global__ void cvtAk(const float* __restrict__ Adf, unsigned short* __restrict__ Adbf) {
    int i = blockIdx.x * blockDim.x + threadIdx.x;
    if (i < Nn * KP) Adbf[i] = (unsigned short)f2bf(Adf[i]);
}

// ---------------------------------------------------------------------------
// W prep: split W[KT][64] -> hi/lo bf16 in B-fragment layout [col][KPAD]
// ---------------------------------------------------------------------------
__global__ __launch_bounds__(256) void wprep(
        const float* __restrict__ W1, const float* __restrict__ W2,
        const float* __restrict__ W3,
        unsigned short* __restrict__ T1h, unsigned short* __restrict__ T1l,
        unsigned short* __restrict__ T2h, unsigned short* __restrict__ T2l,
        unsigned short* __restrict__ T3h, unsigned short* __restrict__ T3l) {
    const int w = blockIdx.x >> 6;        // 0,1,2
    const int c = blockIdx.x & 63;
    const float* W = (w == 0) ? W1 : (w == 1) ? W2 : W3;
    const int KT   = (w == 0) ? FIN : Hh;
    const int KPAD = (w == 0) ? 416 : 64;
    unsigned short* Th = (w == 0) ? T1h : (w == 1) ? T2h : T3h;
    unsigned short* Tl = (w == 0) ? T1l : (w == 1) ? T2l : T3l;

    for (int k = threadIdx.x; k < KPAD; k += 256) {
        float v = (k < KT) ? W[k * 64 + c] : 0.f;
        unsigned int hb = f2bf(v);
        Th[c * KPAD + k] = (unsigned short)hb;
        Tl[c * KPAD + k] = (unsigned short)f2bf(v - bf2f(hb));
    }
}

// ---------------------------------------------------------------------------
// Layer-1 GEMM (split precision, LDS-free, pipelined) — R8-proven:
//   Ut = x[M,400](f32) @ W1[400,64]  -> bf16, transposed per batch
// ---------------------------------------------------------------------------
__global__ __launch_bounds__(256) void xg400(
        const float* __restrict__ A,
        const unsigned short* __restrict__ Wth,
        const unsigned short* __restrict__ Wtl,
        unsigned short* __restrict__ Ut) {
    const int tid  = threadIdx.x;
    const int wv   = tid >> 6;
    const int lane = tid & 63;
    const int cl   = lane & 15;
    const int g    = lane >> 4;
    const int m0   = blockIdx.x * 128;
    const int rowA = m0 + wv * 32 + cl;
    const int rowB = rowA + 16;

    f32x4 acc[2][4];
#pragma unroll
    for (int t2 = 0; t2 < 2; ++t2)
#pragma unroll
        for (int n = 0; n < 4; ++n) acc[t2][n] = f32x4{0.f, 0.f, 0.f, 0.f};

    auto loadA = [&](int s, float4& l0, float4& h0, float4& l1, float4& h1) {
        int kk = s * 32 + g * 8;
        int kc = kk > 392 ? 392 : kk;                 // clamp (W pad is zero)
        const float* p = &A[(size_t)rowA * FIN + kc];
        l0 = *reinterpret_cast<const float4*>(p);
        h0 = *reinterpret_cast<const float4*>(p + 4);
        const float* q = &A[(size_t)rowB * FIN + kc];
        l1 = *reinterpret_cast<const float4*>(q);
        h1 = *reinterpret_cast<const float4*>(q + 4);
    };
    auto loadW = [&](int s, u32x4* dst) {
        int kk = s * 32 + g * 8;
#pragma unroll
        for (int n = 0; n < 4; ++n) {
            dst[n]     = *reinterpret_cast<const u32x4*>(&Wth[(size_t)(n * 16 + cl) * 416 + kk]);
            dst[4 + n] = *reinterpret_cast<const u32x4*>(&Wtl[(size_t)(n * 16 + cl) * 416 + kk]);
        }
    };
    auto split = [&](const float4& lo, const float4& hi, bf16x8& ah, bf16x8& al) {
        float v0 = lo.x, v1 = lo.y, v2 = lo.z, v3 = lo.w;
        float v4 = hi.x, v5 = hi.y, v6 = hi.z, v7 = hi.w;
        unsigned h0, h1;
        u32x4 hw, lw;
        h0 = f2bf(v0); h1 = f2bf(v1);
        hw[0] = h0 | (h1 << 16);
        lw[0] = f2bf(v0 - bf2f(h0)) | (f2bf(v1 - bf2f(h1)) << 16);
        h0 = f2bf(v2); h1 = f2bf(v3);
        hw[1] = h0 | (h1 << 16);
        lw[1] = f2bf(v2 - bf2f(h0)) | (f2bf(v3 - bf2f(h1)) << 16);
        h0 = f2bf(v4); h1 = f2bf(v5);
        hw[2] = h0 | (h1 << 16);
        lw[2] = f2bf(v4 - bf2f(h0)) | (f2bf(v5 - bf2f(h1)) << 16);
        h0 = f2bf(v6); h1 = f2bf(v7);
        hw[3] = h0 | (h1 << 16);
        lw[3] = f2bf(v6 - bf2f(h0)) | (f2bf(v7 - bf2f(h1)) << 16);
        ah = __builtin_bit_cast(bf16x8, hw);
        al = __builtin_bit_cast(bf16x8, lw);
    };

    float4 cAl0, cAh0, cAl1, cAh1, nAl0, nAh0, nAl1, nAh1;
    u32x4  cW[8], nW[8];
    loadA(0, cAl0, cAh0, cAl1, cAh1);
    loadW(0, cW);

    for (int s = 0; s < 13; ++s) {
        if (s < 12) {
            loadA(s + 1, nAl0, nAh0, nAl1, nAh1);
            loadW(s + 1, nW);
        }
        bf16x8 ah0, al0, ah1, al1;
        split(cAl0, cAh0, ah0, al0);
        split(cAl1, cAh1, ah1, al1);
#pragma unroll
        for (int n = 0; n < 4; ++n) {
            bf16x8 bh = __builtin_bit_cast(bf16x8, cW[n]);
            bf16x8 bl = __builtin_bit_cast(bf16x8, cW[4 + n]);
            acc[0][n] = __builtin_amdgcn_mfma_f32_16x16x32_bf16(ah0, bh, acc[0][n], 0, 0, 0);
            acc[0][n] = __builtin_amdgcn_mfma_f32_16x16x32_bf16(ah0, bl, acc[0][n], 0, 0, 0);
            acc[0][n] = __builtin_amdgcn_mfma_f32_16x16x32_bf16(al0, bh, acc[0][n], 0, 0, 0);
            acc[1][n] = __builtin_amdgcn_mfma_f32_16x16x32_bf16(ah1, bh, acc[1][n], 0, 0, 0);
            acc[1][n] = __builtin_amdgcn_mfma_f32_16x16x32_bf16(ah1, bl, acc[1][n], 0, 0, 0);
            acc[1][n] = __builtin_amdgcn_mfma_f32_16x16x32_bf16(al1, bh, acc[1][n], 0, 0, 0);
        }
        if (s < 12) {
            cAl0 = nAl0; cAh0 = nAh0; cAl1 = nAl1; cAh1 = nAh1;
#pragma unroll
            for (int j = 0; j < 8; ++j) cW[j] = nW[j];
        }
    }

#pragma unroll
    for (int t2 = 0; t2 < 2; ++t2) {
        const int row0  = m0 + wv * 32 + t2 * 16 + g * 4;
        const int b     = row0 / Nn;
        const int node0 = row0 - b * Nn;
#pragma unroll
        for (int n = 0; n < 4; ++n) {
            const int col = n * 16 + cl;
            u32x2 pk;
            pk[0] = f2bf(acc[t2][n][0]) | (f2bf(acc[t2][n][1]) << 16);
            pk[1] = f2bf(acc[t2][n][2]) | (f2bf(acc[t2][n][3]) << 16);
            *reinterpret_cast<u32x2*>(&Ut[((size_t)b * 64 + col) * UTP + node0]) = pk;
        }
    }
}

// ---------------------------------------------------------------------------
// Layer-1 aggregation (R9-proven): Z[b] = relu(normalize(Adj@U[b] + b1)),
// + BN stats. 4 blocks per batch, reads Ut from global.
// ---------------------------------------------------------------------------
__global__ __launch_bounds__(256) void aggmm(
        const unsigned short* __restrict__ Ad,
        const unsigned short* __restrict__ Ut,
        const float* __restrict__ bias,
        float* __restrict__ Zout,
        float* __restrict__ ssum, float* __restrict__ ssq) {
    const int b    = blockIdx.x >> 2;
    const int q    = blockIdx.x & 3;
    const int tid  = threadIdx.x;
    const int lane = tid & 63;
    const int wv   = tid >> 6;
    const int cl   = lane & 15;
    const int g    = lane >> 4;
    const unsigned short* __restrict__ Ub = Ut + (size_t)b * 64 * UTP;

    f32x4 acc[2][4];
#pragma unroll
    for (int i = 0; i < 2; ++i)
#pragma unroll
        for (int n = 0; n < 4; ++n) acc[i][n] = f32x4{0.f, 0.f, 0.f, 0.f};

    for (int k0 = 0; k0 < KP; k0 += 32) {
        const int kk = k0 + g * 8;
        bf16x8 bf[4];
#pragma unroll
        for (int n = 0; n < 4; ++n) {
            u32x4 w = *reinterpret_cast<const u32x4*>(&Ub[(size_t)(n * 16 + cl) * UTP + kk]);
            bf[n] = __builtin_bit_cast(bf16x8, w);
        }
#pragma unroll
        for (int i = 0; i < 2; ++i) {
            const int t = q + 4 * wv + 16 * i;
            if (t < 25) {
                const int row = t * 16 + cl;
                u32x4 ar = *reinterpret_cast<const u32x4*>(&Ad[(size_t)row * KP + kk]);
                bf16x8 af = __builtin_bit_cast(bf16x8, ar);
#pragma unroll
                for (int n = 0; n < 4; ++n)
                    acc[i][n] = __builtin_amdgcn_mfma_f32_16x16x32_bf16(
                        af, bf[n], acc[i][n], 0, 0, 0);
            }
        }
    }

    float bv[4];
#pragma unroll
    for (int n = 0; n < 4; ++n) bv[n] = bias[n * 16 + cl];

#pragma unroll
    for (int i = 0; i < 2; ++i) {
        const int t = q + 4 * wv + 16 * i;
        if (t < 25) {
            float y[4][4];
#pragma unroll
            for (int n = 0; n < 4; ++n)
#pragma unroll
                for (int r = 0; r < 4; ++r) y[n][r] = acc[i][n][r] + bv[n];

            float pss[4];
#pragma unroll
            for (int r = 0; r < 4; ++r)
                pss[r] = y[0][r]*y[0][r] + y[1][r]*y[1][r] +
                         y[2][r]*y[2][r] + y[3][r]*y[3][r];
#pragma unroll
            for (int m = 1; m < 16; m <<= 1)
#pragma unroll
                for (int r = 0; r < 4; ++r) pss[r] += __shfl_xor(pss[r], m);

            float rin[4];
#pragma unroll
            for (int r = 0; r < 4; ++r)
                rin[r] = 1.f / fmaxf(sqrtf(pss[r]), 1e-12f);

            float s1[4], s2[4];
#pragma unroll
            for (int r = 0; r < 4; ++r) { s1[r] = 0.f; s2[r] = 0.f; }
#pragma unroll
            for (int n = 0; n < 4; ++n)
#pragma unroll
                for (int r = 0; r < 4; ++r) {
                    float z = fmaxf(y[n][r] * rin[r], 0.f);
                    const int row = t * 16 + g * 4 + r;
                    Zout[((size_t)b * Nn + row) * Hh + n * 16 + cl] = z;
                    s1[r] += z;
                    s2[r] += z * z;
                }
#pragma unroll
            for (int m = 1; m < 16; m <<= 1)
#pragma unroll
                for (int r = 0; r < 4; ++r) {
                    s1[r] += __shfl_xor(s1[r], m);
                    s2[r] += __shfl_xor(s2[r], m);
                }
            if (cl == 0) {
#pragma unroll
                for (int r = 0; r < 4; ++r) {
                    const int row = t * 16 + g * 4 + r;
                    atomicAdd(&ssum[row], s1[r]);
                    atomicAdd(&ssq[row],  s2[r]);
                }
            }
        }
    }
}

__global__ void finalize_stats(const float* __restrict__ ssum,
                               const float* __restrict__ ssq,
                               float* __restrict__ mean, float* __restrict__ inv) {
    int r = threadIdx.x;
    if (r < Nn) {
        float m = ssum[r] * (1.0f / BH_COUNT);
        float v = ssq[r] * (1.0f / BH_COUNT) - m * m;
        mean[r] = m;
        inv[r]  = rsqrtf(v + 1e-5f);
    }
}

// ---------------------------------------------------------------------------
// Fused layer 2/3: block = ONE BATCH (grid 256), now 1024 thr = 16 waves.
// Phase A (2 tiles/wave, both Z-loads prefetched):
//   za = (Zin[b,node]-mean[node])*inv[node];  track max(za) -> outmax_za
//   U = za @ W (split-precision MFMA) -> LDS Us[col][node] bf16 (UPAD=420)
// sync
// Phase B (single K sweep, 2 live tiles t=wv+16i, t<25):
//   Y = Adj @ U + bias;  z = normalize(Y)
//   STATS: z=relu(z) -> Zout + BN stat atomics
//   else : z -> x3 (d_out) + block-local column max -> out3
// Per-element arithmetic identical to R10 (same f2bf points, MFMA order).
// ---------------------------------------------------------------------------
template <bool STATS>
__global__ __launch_bounds__(1024) void fusedl(
        const float* __restrict__ Zin,
        const unsigned short* __restrict__ Ad,
        const unsigned short* __restrict__ Wth,   // [64][64] frag layout
        const unsigned short* __restrict__ Wtl,
        const float* __restrict__ mean, const float* __restrict__ inv,
        const float* __restrict__ bias,
        float* __restrict__ Zout,                 // Z (STATS) or x3 (d_out)
        float* __restrict__ ssum, float* __restrict__ ssq,
        float* __restrict__ outmax_za,            // out1 / out2 [B][64]
        float* __restrict__ out3) {               // [B][64] (!STATS)
    __shared__ unsigned short Us[64 * UPAD];      // 53760 B
    __shared__ float sred[16][64];                // 4096 B
    const int b    = blockIdx.x;
    const int tid  = threadIdx.x;
    const int wv   = tid >> 6;                    // 0..15
    const int lane = tid & 63;
    const int cl   = lane & 15;
    const int g    = lane >> 4;

    // zero LDS pad rows (node 400..419)
    for (int i = tid; i < 64 * (UPAD - Nn); i += 1024) {
        int c = i / (UPAD - Nn), k = Nn + i % (UPAD - Nn);
        Us[c * UPAD + k] = 0;
    }

    // ---- Phase A: prefetch both tiles' Z, affine + max + za@W -> LDS ----
    const int t0 = wv;            // < 16 < 25 always
    const int t1 = wv + 16;       // valid iff < 25 (wv < 9)
    const bool has1 = (t1 < 25);

    float za0[16], za1[16];
    {
        const int node = t0 * 16 + cl;
        const float mm = mean[node], iv = inv[node];
#pragma unroll
        for (int s = 0; s < 2; ++s) {
            const float* p = &Zin[((size_t)b * Nn + node) * 64 + s * 32 + g * 8];
            float4 lo = *reinterpret_cast<const float4*>(p);
            float4 hi = *reinterpret_cast<const float4*>(p + 4);
            za0[s * 8 + 0] = (lo.x - mm) * iv;
            za0[s * 8 + 1] = (lo.y - mm) * iv;
            za0[s * 8 + 2] = (lo.z - mm) * iv;
            za0[s * 8 + 3] = (lo.w - mm) * iv;
            za0[s * 8 + 4] = (hi.x - mm) * iv;
            za0[s * 8 + 5] = (hi.y - mm) * iv;
            za0[s * 8 + 6] = (hi.z - mm) * iv;
            za0[s * 8 + 7] = (hi.w - mm) * iv;
        }
    }
    if (has1) {
        const int node = t1 * 16 + cl;
        const float mm = mean[node], iv = inv[node];
#pragma unroll
        for (int s = 0; s < 2; ++s) {
            const float* p = &Zin[((size_t)b * Nn + node) * 64 + s * 32 + g * 8];
            float4 lo = *reinterpret_cast<const float4*>(p);
            float4 hi = *reinterpret_cast<const float4*>(p + 4);
            za1[s * 8 + 0] = (lo.x - mm) * iv;
            za1[s * 8 + 1] = (lo.y - mm) * iv;
            za1[s * 8 + 2] = (lo.z - mm) * iv;
            za1[s * 8 + 3] = (lo.w - mm) * iv;
            za1[s * 8 + 4] = (hi.x - mm) * iv;
            za1[s * 8 + 5] = (hi.y - mm) * iv;
            za1[s * 8 + 6] = (hi.z - mm) * iv;
            za1[s * 8 + 7] = (hi.w - mm) * iv;
        }
    }

    float vmax[16];
#pragma unroll
    for (int j = 0; j < 16; ++j) {
        vmax[j] = za0[j];
        if (has1) vmax[j] = fmaxf(vmax[j], za1[j]);
    }

    auto processA = [&](int t, const float* za) {
        f32x4 acc[4];
#pragma unroll
        for (int n = 0; n < 4; ++n) acc[n] = f32x4{0.f, 0.f, 0.f, 0.f};
#pragma unroll
        for (int s = 0; s < 2; ++s) {
            u32x4 hw, lw;
#pragma unroll
            for (int j = 0; j < 4; ++j) {
                unsigned h0 = f2bf(za[s * 8 + 2 * j]);
                unsigned h1 = f2bf(za[s * 8 + 2 * j + 1]);
                hw[j] = h0 | (h1 << 16);
                lw[j] = f2bf(za[s * 8 + 2 * j] - bf2f(h0)) |
                        (f2bf(za[s * 8 + 2 * j + 1] - bf2f(h1)) << 16);
            }
            bf16x8 ah = __builtin_bit_cast(bf16x8, hw);
            bf16x8 al = __builtin_bit_cast(bf16x8, lw);
            const int kk = s * 32 + g * 8;
#pragma unroll
            for (int n = 0; n < 4; ++n) {
                u32x4 bhw = *reinterpret_cast<const u32x4*>(&Wth[(size_t)(n * 16 + cl) * 64 + kk]);
                u32x4 blw = *reinterpret_cast<const u32x4*>(&Wtl[(size_t)(n * 16 + cl) * 64 + kk]);
                bf16x8 bh = __builtin_bit_cast(bf16x8, bhw);
                bf16x8 bl = __builtin_bit_cast(bf16x8, blw);
                acc[n] = __builtin_amdgcn_mfma_f32_16x16x32_bf16(ah, bh, acc[n], 0, 0, 0);
                acc[n] = __builtin_amdgcn_mfma_f32_16x16x32_bf16(ah, bl, acc[n], 0, 0, 0);
                acc[n] = __builtin_amdgcn_mfma_f32_16x16x32_bf16(al, bh, acc[n], 0, 0, 0);
            }
        }
        const int node0 = t * 16 + g * 4;
#pragma unroll
        for (int n = 0; n < 4; ++n) {
            const int col = n * 16 + cl;
            u32x2 pk;
            pk[0] = f2bf(acc[n][0]) | (f2bf(acc[n][1]) << 16);
            pk[1] = f2bf(acc[n][2]) | (f2bf(acc[n][3]) << 16);
            *reinterpret_cast<u32x2*>(&Us[col * UPAD + node0]) = pk;
        }
    };
    processA(t0, za0);
    if (has1) processA(t1, za1);

    // za-max: reduce over cl (nodes within wave), stash per wave
#pragma unroll
    for (int m = 1; m < 16; m <<= 1)
#pragma unroll
        for (int j = 0; j < 16; ++j)
            vmax[j] = fmaxf(vmax[j], __shfl_xor(vmax[j], m));
    if (cl == 0) {
#pragma unroll
        for (int j = 0; j < 16; ++j) {
            const int h = 32 * (j >> 3) + g * 8 + (j & 7);
            sred[wv][h] = vmax[j];
        }
    }
    __syncthreads();          // covers Us writes + sred
    if (tid < 64) {
        float m = sred[0][tid];
#pragma unroll
        for (int w = 1; w < 16; ++w) m = fmaxf(m, sred[w][tid]);
        outmax_za[b * 64 + tid] = m;
    }

    // ---- Phase B: Adj @ U (from LDS), single K sweep, 2 live tiles ----
    const float bvs[4] = {bias[cl], bias[16 + cl], bias[32 + cl], bias[48 + cl]};
    float pmax[4];
#pragma unroll
    for (int n = 0; n < 4; ++n) pmax[n] = -3.4e38f;

    f32x4 acc[2][4];
#pragma unroll
    for (int i = 0; i < 2; ++i)
#pragma unroll
        for (int n = 0; n < 4; ++n) acc[i][n] = f32x4{0.f, 0.f, 0.f, 0.f};

    for (int k0 = 0; k0 < KP; k0 += 32) {
        const int kk = k0 + g * 8;
        bf16x8 bf[4];
#pragma unroll
        for (int n = 0; n < 4; ++n) {
            const unsigned short* p = &Us[(n * 16 + cl) * UPAD + kk];
            u32x2 lo = *reinterpret_cast<const u32x2*>(p);
            u32x2 hi = *reinterpret_cast<const u32x2*>(p + 4);
            u32x4 w; w[0] = lo[0]; w[1] = lo[1]; w[2] = hi[0]; w[3] = hi[1];
            bf[n] = __builtin_bit_cast(bf16x8, w);
        }
#pragma unroll
        for (int i = 0; i < 2; ++i) {
            const int t = wv + 16 * i;
            if (t < 25) {
                const int row = t * 16 + cl;
                u32x4 ar = *reinterpret_cast<const u32x4*>(&Ad[(size_t)row * KP + kk]);
                bf16x8 af = __builtin_bit_cast(bf16x8, ar);
#pragma unroll
                for (int n = 0; n < 4; ++n)
                    acc[i][n] = __builtin_amdgcn_mfma_f32_16x16x32_bf16(
                        af, bf[n], acc[i][n], 0, 0, 0);
            }
        }
    }

#pragma unroll
    for (int i = 0; i < 2; ++i) {
        const int t = wv + 16 * i;
        if (t < 25) {
            float y[4][4];
#pragma unroll
            for (int n = 0; n < 4; ++n)
#pragma unroll
                for (int r = 0; r < 4; ++r) y[n][r] = acc[i][n][r] + bvs[n];

            float pss[4];
#pragma unroll
            for (int r = 0; r < 4; ++r)
                pss[r] = y[0][r]*y[0][r] + y[1][r]*y[1][r] +
                         y[2][r]*y[2][r] + y[3][r]*y[3][r];
#pragma unroll
            for (int m = 1; m < 16; m <<= 1)
#pragma unroll
                for (int r = 0; r < 4; ++r) pss[r] += __shfl_xor(pss[r], m);

            float rin[4];
#pragma unroll
            for (int r = 0; r < 4; ++r)
                rin[r] = 1.f / fmaxf(sqrtf(pss[r]), 1e-12f);

            float s1[4], s2a[4];
#pragma unroll
            for (int r = 0; r < 4; ++r) { s1[r] = 0.f; s2a[r] = 0.f; }
#pragma unroll
            for (int n = 0; n < 4; ++n)
#pragma unroll
                for (int r = 0; r < 4; ++r) {
                    float z = y[n][r] * rin[r];
                    if (STATS) z = fmaxf(z, 0.f);
                    const int row = t * 16 + g * 4 + r;
                    Zout[((size_t)b * Nn + row) * Hh + n * 16 + cl] = z;
                    if (STATS) { s1[r] += z; s2a[r] += z * z; }
                    else        pmax[n] = fmaxf(pmax[n], z);
                }

            if (STATS) {
#pragma unroll
                for (int m = 1; m < 16; m <<= 1)
#pragma unroll
                    for (int r = 0; r < 4; ++r) {
                        s1[r]  += __shfl_xor(s1[r], m);
                        s2a[r] += __shfl_xor(s2a[r], m);
                    }
                if (cl == 0) {
#pragma unroll
                    for (int r = 0; r < 4; ++r) {
                        const int row = t * 16 + g * 4 + r;
                        atomicAdd(&ssum[row], s1[r]);
                        atomicAdd(&ssq[row],  s2a[r]);
                    }
                }
            }
        }
    }

    if constexpr (!STATS) {
        // block-local column max over all 400 rows -> out3[b][h]
        __syncthreads();
#pragma unroll
        for (int m = 16; m < 64; m <<= 1)
#pragma unroll
            for (int n = 0; n < 4; ++n)
                pmax[n] = fmaxf(pmax[n], __shfl_xor(pmax[n], m));
        if (lane < 16) {
#pragma unroll
            for (int n = 0; n < 4; ++n) sred[wv][n * 16 + cl] = pmax[n];
        }
        __syncthreads();
        if (tid < 64) {
            float m = sred[0][tid];
#pragma unroll
            for (int w = 1; w < 16; ++w) m = fmaxf(m, sred[w][tid]);
            out3[b * 64 + tid] = m;
        }
    }
}

// ---------------------------------------------------------------------------
// FC head: h=[out1|out2|out3] (256x192) -> fc1+relu+bn2 -> fc2+relu+bn2 -> fc3
// ---------------------------------------------------------------------------
__global__ __launch_bounds__(1024) void headk(
        const float* __restrict__ out1, const float* __restrict__ out2,
        const float* __restrict__ out3,
        const float* __restrict__ W1f, const float* __restrict__ b1f,
        const float* __restrict__ W2f, const float* __restrict__ b2f,
        const float* __restrict__ W3f, const float* __restrict__ b3f,
        float* __restrict__ ypred) {
    __shared__ float gA[256][64];     // 64 KB activations
    __shared__ float w1s[192 * 64];   // 48 KB
    __shared__ float w2s[64 * 64];    // 16 KB
    __shared__ float mS[64], iS[64];
    const int t = threadIdx.x;
    const int r = t >> 2, q = t & 3;

    for (int i = t; i < 192 * 64; i += 1024) w1s[i] = W1f[i];
    for (int i = t; i < 64 * 64; i += 1024) w2s[i] = W2f[i];
    __syncthreads();

    float acc[16];
#pragma unroll
    for (int j = 0; j < 16; ++j) acc[j] = b1f[q * 16 + j];
    for (int k = 0; k < 192; ++k) {
        float hv = (k < 64) ? out1[r * 64 + k]
                 : (k < 128) ? out2[r * 64 + (k - 64)]
                             : out3[r * 64 + (k - 128)];
#pragma unroll
        for (int j = 0; j < 16; ++j) acc[j] += hv * w1s[k * 64 + q * 16 + j];
    }
#pragma unroll
    for (int j = 0; j < 16; ++j) gA[r][q * 16 + j] = fmaxf(acc[j], 0.f);
    __syncthreads();

    if (t < 64) {
        float s = 0.f, s2 = 0.f;
        for (int rr = 0; rr < 256; ++rr) { float v = gA[rr][t]; s += v; s2 += v * v; }
        float m = s * (1.f / 256.f);
        float var = s2 * (1.f / 256.f) - m * m;
        mS[t] = m;
        iS[t] = rsqrtf(var + 1e-5f);
    }
    __syncthreads();

#pragma unroll
    for (int j = 0; j < 16; ++j) acc[j] = b2f[q * 16 + j];
#pragma unroll
    for (int k = 0; k < 64; ++k) {
        float gn = (gA[r][k] - mS[k]) * iS[k];
#pragma unroll
        for (int j = 0; j < 16; ++j) acc[j] += gn * w2s[k * 64 + q * 16 + j];
    }
    __syncthreads();
#pragma unroll
    for (int j = 0; j < 16; ++j) gA[r][q * 16 + j] = fmaxf(acc[j], 0.f);
    __syncthreads();

    if (t < 64) {
        float s = 0.f, s2 = 0.f;
        for (int rr = 0; rr < 256; ++rr) { float v = gA[rr][t]; s += v; s2 += v * v; }
        float m = s * (1.f / 256.f);
        float var = s2 * (1.f / 256.f) - m * m;
        mS[t] = m;
        iS[t] = rsqrtf(var + 1e-5f);
    }
    __syncthreads();

    if (q < 2) {
        float a = b3f[q];
#pragma unroll
        for (int k = 0; k < 64; ++k) {
            float gn = (gA[r][k] - mS[k]) * iS[k];
            a += gn * W3f[k * 2 + q];
        }
        ypred[r * 2 + q] = a;
    }
}

// ---------------------------------------------------------------------------
extern "C" void kernel_launch(void* const* d_in, const int* in_sizes, int n_in,
                              void* d_out, int out_size, void* d_ws, size_t ws_size,
                              hipStream_t stream) {
    const float* x    = (const float*)d_in[0];
    const int*   arow = (const int*)d_in[1];
    const int*   acol = (const int*)d_in[2];
    const float* aval = (const float*)d_in[3];
    const float* W1 = (const float*)d_in[4];
    const float* b1 = (const float*)d_in[5];
    const float* W2 = (const float*)d_in[6];
    const float* b2 = (const float*)d_in[7];
    const float* W3 = (const float*)d_in[8];
    const float* b3 = (const float*)d_in[9];
    const float* fc1W = (const float*)d_in[10];
    const float* fc1b = (const float*)d_in[11];
    const float* fc2W = (const float*)d_in[12];
    const float* fc2b = (const float*)d_in[13];
    const float* fc3W = (const float*)d_in[14];
    const float* fc3b = (const float*)d_in[15];

    char* w = (char*)d_ws;
    size_t off = 0;
    float* Adf = (float*)(w + off);            off += (size_t)Nn * KP * 4;
    unsigned short* Adbf = (unsigned short*)(w + off); off += (size_t)Nn * KP * 2;
    unsigned short* T1h = (unsigned short*)(w + off); off += (size_t)64 * 416 * 2;
    unsigned short* T1l = (unsigned short*)(w + off); off += (size_t)64 * 416 * 2;
    unsigned short* T2h = (unsigned short*)(w + off); off += (size_t)64 * 64 * 2;
    unsigned short* T2l = (unsigned short*)(w + off); off += (size_t)64 * 64 * 2;
    unsigned short* T3h = (unsigned short*)(w + off); off += (size_t)64 * 64 * 2;
    unsigned short* T3l = (unsigned short*)(w + off); off += (size_t)64 * 64 * 2;
    unsigned short* Ut = (unsigned short*)(w + off); off += (size_t)Bb * 64 * UTP * 2;
    float* Z1 = (float*)(w + off);             off += (size_t)Mrows * Hh * 4;
    float* Z2 = (float*)(w + off);             off += (size_t)Mrows * Hh * 4;
    float* stats = (float*)(w + off);          off += 1600 * 4;
    float* ssum1 = stats, *ssq1 = stats + 400, *ssum2 = stats + 800, *ssq2 = stats + 1200;
    float* mean1 = (float*)(w + off); off += 1600;
    float* inv1  = (float*)(w + off); off += 1600;
    float* mean2 = (float*)(w + off); off += 1600;
    float* inv2  = (float*)(w + off); off += 1600;
    float* out1  = (float*)(w + off); off += Bb * Hh * 4;
    float* out2  = (float*)(w + off); off += Bb * Hh * 4;
    float* out3  = (float*)(w + off); off += Bb * Hh * 4;

    float* ypred = (float*)d_out;
    float* x3    = (float*)d_out + 512;

    // Prep: densify adjacency (bf16 [400][416]) + split weights
    initk<<<384, 1024, 0, stream>>>(Adf, stats, Ut);
    scatAk<<<(NNZ + 255) / 256, 256, 0, stream>>>(arow, acol, aval, Adf);
    cvtAk<<<(Nn * KP + 1023) / 1024, 1024, 0, stream>>>(Adf, Adbf);
    wprep<<<192, 256, 0, stream>>>(W1, W2, W3, T1h, T1l, T2h, T2l, T3h, T3l);

    // Layer 1
    xg400<<<Mrows / 128, 256, 0, stream>>>(x, T1h, T1l, Ut);
    aggmm<<<Bb * 4, 256, 0, stream>>>(Adbf, Ut, b1, Z1, ssum1, ssq1);
    finalize_stats<<<1, 512, 0, stream>>>(ssum1, ssq1, mean1, inv1);

    // Layer 2 fused: BN1 affine + out1-max + za@W2 (LDS) + Adj@U2 + stats2
    fusedl<true><<<Bb, 1024, 0, stream>>>(Z1, Adbf, T2h, T2l, mean1, inv1, b2,
                                          Z2, ssum2, ssq2, out1, nullptr);
    finalize_stats<<<1, 512, 0, stream>>>(ssum2, ssq2, mean2, inv2);

    // Layer 3 fused: BN2 affine + out2-max + za@W3 (LDS) + Adj@U3 -> x3 + out3
    fusedl<false><<<Bb, 1024, 0, stream>>>(Z2, Adbf, T3h, T3l, mean2, inv2, b3,
                                           x3, nullptr, nullptr, out2, out3);

    // FC head
    headk<<<1, 1024, 0, stream>>>(out1, out2, out3, fc1W, fc1b, fc2W, fc2b,
                                  fc3W, fc3b, ypred);
}